// Round 4
// baseline (2219.656 us; speedup 1.0000x reference)
//
#include <hip/hip_runtime.h>

#define NN 40000
#define DDEG 16
#define FF 128
#define OO 128
#define NG 512   // 4*F gates

typedef short  s16x8 __attribute__((ext_vector_type(8)));
typedef unsigned short u16x8 __attribute__((ext_vector_type(8)));
typedef float  f32x4 __attribute__((ext_vector_type(4)));

static_assert(sizeof(s16x8) == 16, "frag size");

__device__ __forceinline__ unsigned short f2bf(float f) {
    unsigned int u = __builtin_bit_cast(unsigned int, f);
    u += 0x7FFFu + ((u >> 16) & 1u);   // RNE
    return (unsigned short)(u >> 16);
}
__device__ __forceinline__ float sigm(float x) {
    return __builtin_amdgcn_rcpf(1.0f + __expf(-x));
}
__device__ __forceinline__ float tanh_(float x) {
    float e = __expf(2.0f * x);
    return (e - 1.0f) * __builtin_amdgcn_rcpf(e + 1.0f);
}
__device__ __forceinline__ f32x4 splat4(float v) { f32x4 r = {v, v, v, v}; return r; }

// ---------------- prep: cast weights to bf16 (+ transpose Ws/Wn to [o][k]) ----
__global__ void k_prep(const float* __restrict__ Wih, const float* __restrict__ Whh,
                       const float* __restrict__ Ws,  const float* __restrict__ Wn,
                       unsigned short* __restrict__ wihb, unsigned short* __restrict__ whhb,
                       unsigned short* __restrict__ wstb, unsigned short* __restrict__ wntb) {
    int i = blockIdx.x * blockDim.x + threadIdx.x;
    int stride = gridDim.x * blockDim.x;
    for (int idx = i; idx < 4 * NG * FF; idx += stride) {
        wihb[idx] = f2bf(Wih[idx]);
        whhb[idx] = f2bf(Whh[idx]);
    }
    for (int idx = i; idx < 4 * FF * OO; idx += stride) {
        int r = idx >> 14;          // /(128*128)
        int rem = idx & 16383;
        int o = rem >> 7;
        int k = rem & 127;
        // dest [r][o][k] <- src [r][k][o]
        wstb[idx] = f2bf(Ws[(r << 14) + (k << 7) + o]);
        wntb[idx] = f2bf(Wn[(r << 14) + (k << 7) + o]);
    }
}

// ---------------- cast feat to bf16 ------------------------------------------
__global__ void k_castfeat(const float* __restrict__ feat, unsigned short* __restrict__ fbf) {
    int i = blockIdx.x * blockDim.x + threadIdx.x;
    int idx = i * 4;
    if (idx < NN * FF) {
        float4 v = *(const float4*)(feat + idx);
        ushort4 o;
        o.x = f2bf(v.x); o.y = f2bf(v.y); o.z = f2bf(v.z); o.w = f2bf(v.w);
        *(ushort4*)(fbf + idx) = o;
    }
}

// ---------------- segment mean (seg_ids sorted, G=64), float4 vectorized -----
__global__ void k_segmean(const float* __restrict__ feat, const int* __restrict__ seg,
                          float* __restrict__ mean) {
    int g = blockIdx.x;
    int lo, hi;
    { int a = 0, b = NN; while (a < b) { int m = (a + b) >> 1; if (seg[m] < g) a = m + 1; else b = m; } lo = a; }
    { int a = 0, b = NN; while (a < b) { int m = (a + b) >> 1; if (seg[m] < g + 1) a = m + 1; else b = m; } hi = a; }
    int tid = threadIdx.x;
    int d4 = tid & 31;          // float4 slot: dims [d4*4, d4*4+4)
    int part = tid >> 5;        // 8 row-partitions
    float4 s = {0.f, 0.f, 0.f, 0.f};
    for (int row = lo + part; row < hi; row += 8) {
        float4 v = *(const float4*)(feat + (size_t)row * FF + d4 * 4);
        s.x += v.x; s.y += v.y; s.z += v.z; s.w += v.w;
    }
    __shared__ float ps[8][128];
    ps[part][d4 * 4 + 0] = s.x; ps[part][d4 * 4 + 1] = s.y;
    ps[part][d4 * 4 + 2] = s.z; ps[part][d4 * 4 + 3] = s.w;
    __syncthreads();
    if (tid < 128) {
        float tot = 0.f;
#pragma unroll
        for (int p = 0; p < 8; ++p) tot += ps[p][tid];
        mean[g * FF + tid] = tot / fmaxf((float)(hi - lo), 1.0f);
    }
}

// ---------------- deg bucketing, all 4 relations -----------------------------
// cnt4[r*64 + d] = counts (d=1..16), cnt4[r*64 + 40 + d] = cursor
__global__ void k_count(const int* __restrict__ D0, const int* __restrict__ D1,
                        const int* __restrict__ D2, const int* __restrict__ D3,
                        int* __restrict__ cnt4) {
    int r = blockIdx.y;
    const int* dg = (r == 0) ? D0 : (r == 1) ? D1 : (r == 2) ? D2 : D3;
    int n = blockIdx.x * blockDim.x + threadIdx.x;
    if (n < NN) { int d = dg[n]; if (d > 0) atomicAdd(&cnt4[r * 64 + d], 1); }
}
__global__ void k_offsets(int* __restrict__ cnt4) {
    int r = threadIdx.x;
    if (r < 4 && blockIdx.x == 0) {
        int running = 0;
        for (int d = 1; d <= 16; ++d) {
            cnt4[r * 64 + 40 + d] = running;
            running += (cnt4[r * 64 + d] + 31) & ~31;   // pad each bucket to x32
        }
    }
}
__global__ void k_scatter(const int* __restrict__ D0, const int* __restrict__ D1,
                          const int* __restrict__ D2, const int* __restrict__ D3,
                          int* __restrict__ cnt4, int* __restrict__ order4) {
    int r = blockIdx.y;
    const int* dg = (r == 0) ? D0 : (r == 1) ? D1 : (r == 2) ? D2 : D3;
    int n = blockIdx.x * blockDim.x + threadIdx.x;
    if (n < NN) {
        int d = dg[n];
        if (d > 0) { int p = atomicAdd(&cnt4[r * 64 + 40 + d], 1); order4[r * 40960 + p] = n; }
    }
}

// ---------------- fused bucketed LSTM (Wih folded into recurrence) ----------
// grid (1280, 4): blockIdx.y = relation r. 256 thr = 4 waves; block owns 32
// nodes of equal deg (two 16-node halves share each B-frag). Wave w owns gate
// tiles {w+4j}; i/f/g/o quadruples thread-local; gather = feat rows (256B)
// prefetched one step ahead; h via double-buffered swizzled LDS, 1 barrier/step.
__global__ __launch_bounds__(256, 2) void k_lstm(const unsigned short* __restrict__ fbf,
                                                 const unsigned short* __restrict__ wihb,
                                                 const unsigned short* __restrict__ whhb,
                                                 const float* __restrict__ lb,
                                                 const int* __restrict__ order4,
                                                 const int* __restrict__ N0, const int* __restrict__ N1,
                                                 const int* __restrict__ N2, const int* __restrict__ N3,
                                                 const int* __restrict__ D0, const int* __restrict__ D1,
                                                 const int* __restrict__ D2, const int* __restrict__ D3,
                                                 unsigned short* __restrict__ hfin4) {
    int r = blockIdx.y;
    const int* nbr = (r == 0) ? N0 : (r == 1) ? N1 : (r == 2) ? N2 : N3;
    const int* deg = (r == 0) ? D0 : (r == 1) ? D1 : (r == 2) ? D2 : D3;
    unsigned short* hfin = hfin4 + (size_t)r * NN * FF;

    __shared__ int nodes[32];
    __shared__ int nbrs[32][16];
    __shared__ unsigned short hbuf[2][4096];   // 2 x (32 rows x 128 dims bf16), XOR-swizzled
    int tid = threadIdx.x;
    int w = tid >> 6, l = tid & 63;
    int g0 = blockIdx.x * 32;
    if (tid < 32) nodes[tid] = order4[r * 40960 + g0 + tid];
    __syncthreads();
    if (nodes[0] < 0) return;
    int degv = deg[nodes[0]];

#pragma unroll
    for (int k = 0; k < 2; ++k) {
        int idx = tid + k * 256;
        int row = idx >> 4, t = idx & 15;
        int nd = nodes[row]; if (nd < 0) nd = 0;
        nbrs[row][t] = nbr[nd * DDEG + t];
    }
    __syncthreads();

    int col = l & 15, grp = l >> 4;
    const unsigned short* wihp = wihb + (size_t)r * NG * FF + col * FF + grp * 8;
    const unsigned short* whhp = whhb + (size_t)r * NG * FF + col * FF + grp * 8;
    const unsigned short* fb = fbf + grp * 8;

    float breg[8];
#pragma unroll
    for (int j = 0; j < 8; ++j) breg[j] = lb[r * NG + (w + 4 * j) * 16 + col];

    float cst[16];
#pragma unroll
    for (int e = 0; e < 16; ++e) cst[e] = 0.f;

    // prefetch A-frags for t=0 (feat rows of first neighbors, both halves)
    s16x8 ac0[4], ac1[4], an0[4], an1[4];
    {
        const unsigned short* p0 = fb + (size_t)nbrs[col][0] * FF;
        const unsigned short* p1 = fb + (size_t)nbrs[16 + col][0] * FF;
#pragma unroll
        for (int kt = 0; kt < 4; ++kt) {
            ac0[kt] = *(const s16x8*)(p0 + kt * 32);
            ac1[kt] = *(const s16x8*)(p1 + kt * 32);
        }
    }

    for (int t = 0; t < degv; ++t) {
        // issue next-step gathers early (overlap with MFMA + activations)
        if (t + 1 < degv) {
            const unsigned short* p0 = fb + (size_t)nbrs[col][t + 1] * FF;
            const unsigned short* p1 = fb + (size_t)nbrs[16 + col][t + 1] * FF;
#pragma unroll
            for (int kt = 0; kt < 4; ++kt) {
                an0[kt] = *(const s16x8*)(p0 + kt * 32);
                an1[kt] = *(const s16x8*)(p1 + kt * 32);
            }
        }
        f32x4 acc0[8], acc1[8];
#pragma unroll
        for (int j = 0; j < 8; ++j) { acc0[j] = splat4(breg[j]); acc1[j] = splat4(breg[j]); }

        // x-part: gates += feat[nbr] @ Wih_tile.T
#pragma unroll
        for (int j = 0; j < 8; ++j) {
#pragma unroll
            for (int kt = 0; kt < 4; ++kt) {
                s16x8 b = *(const s16x8*)(wihp + (size_t)(w + 4 * j) * 16 * FF + kt * 32);
                acc0[j] = __builtin_amdgcn_mfma_f32_16x16x32_bf16(ac0[kt], b, acc0[j], 0, 0, 0);
                acc1[j] = __builtin_amdgcn_mfma_f32_16x16x32_bf16(ac1[kt], b, acc1[j], 0, 0, 0);
            }
        }
        // h-part: gates += h @ Whh_tile.T
        if (t > 0) {
            const char* hrd = (const char*)hbuf[t & 1];
            s16x8 ah0[4], ah1[4];
#pragma unroll
            for (int kt = 0; kt < 4; ++kt) {
                int b0 = (col * 256 + kt * 64 + grp * 16) ^ ((col & 7) << 4);
                ah0[kt] = *(const s16x8*)(hrd + b0);
                ah1[kt] = *(const s16x8*)(hrd + 4096 + b0);   // rows 16..31
            }
#pragma unroll
            for (int j = 0; j < 8; ++j) {
#pragma unroll
                for (int kt = 0; kt < 4; ++kt) {
                    s16x8 b = *(const s16x8*)(whhp + (size_t)(w + 4 * j) * 16 * FF + kt * 32);
                    acc0[j] = __builtin_amdgcn_mfma_f32_16x16x32_bf16(ah0[kt], b, acc0[j], 0, 0, 0);
                    acc1[j] = __builtin_amdgcn_mfma_f32_16x16x32_bf16(ah1[kt], b, acc1[j], 0, 0, 0);
                }
            }
        }
        // in-register activations; write h to the other buffer
        char* hwr = (char*)hbuf[(t + 1) & 1];
#pragma unroll
        for (int s = 0; s < 2; ++s) {
#pragma unroll
            for (int ji = 0; ji < 2; ++ji) {
#pragma unroll
                for (int q = 0; q < 4; ++q) {
                    float iv, fv, gv, ov;
                    if (s == 0) { iv = sigm(acc0[ji][q]); fv = sigm(acc0[ji + 2][q]);
                                  gv = tanh_(acc0[ji + 4][q]); ov = sigm(acc0[ji + 6][q]); }
                    else        { iv = sigm(acc1[ji][q]); fv = sigm(acc1[ji + 2][q]);
                                  gv = tanh_(acc1[ji + 4][q]); ov = sigm(acc1[ji + 6][q]); }
                    int ci = s * 8 + ji * 4 + q;
                    float cv = fv * cst[ci] + iv * gv;
                    cst[ci] = cv;
                    float hv = ov * tanh_(cv);
                    int node = s * 16 + grp * 4 + q;
                    int dim = (w + 4 * ji) * 16 + col;
                    int byte = (node * 256 + dim * 2) ^ ((node & 7) << 4);
                    *(unsigned short*)(hwr + byte) = f2bf(hv);
                }
            }
        }
        // rotate prefetched A-frags
#pragma unroll
        for (int kt = 0; kt < 4; ++kt) { ac0[kt] = an0[kt]; ac1[kt] = an1[kt]; }
        __syncthreads();
    }
    // write h_fin from hbuf[degv & 1]; 32 rows x 256B, 32B per thread
    const char* hf = (const char*)hbuf[degv & 1];
    int row = tid >> 3;
    int nd = nodes[row];
    if (nd >= 0) {
        int off = (tid & 7) * 32;                     // byte within row
#pragma unroll
        for (int h = 0; h < 2; ++h) {
            int byte = (row * 256 + off + h * 16) ^ ((row & 7) << 4);
            u16x8 v = *(const u16x8*)(hf + byte);
            *(u16x8*)(hfin + (size_t)nd * FF + (off + h * 16) / 2) = v;
        }
    }
}

// ---------------- fused projection: all 4 r + max/add + residual -------------
__global__ __launch_bounds__(256, 2) void k_proj(const unsigned short* __restrict__ fbf,
                                                 const unsigned short* __restrict__ hfin4,
                                                 const unsigned short* __restrict__ wstb,
                                                 const unsigned short* __restrict__ wntb,
                                                 const float* __restrict__ bo,
                                                 const float* __restrict__ mean,
                                                 const int* __restrict__ seg,
                                                 float* __restrict__ out) {
    int wv = threadIdx.x >> 6, l = threadIdx.x & 63;
    int n0 = blockIdx.x * 64 + wv * 16;
    int col = l & 15, grp = l >> 4;

    s16x8 af[4];
    const unsigned short* fp = fbf + (size_t)(n0 + col) * FF + grp * 8;
#pragma unroll
    for (int kt = 0; kt < 4; ++kt) af[kt] = *(const s16x8*)(fp + kt * 32);

    f32x4 m01[8], m23[8];
#pragma unroll
    for (int r = 0; r < 4; ++r) {
        f32x4 acc[8];
#pragma unroll
        for (int t = 0; t < 8; ++t) acc[t] = splat4(bo[r * OO + t * 16 + col]);

        const unsigned short* wsb = wstb + (size_t)r * OO * FF + col * FF + grp * 8;
        const unsigned short* wnb = wntb + (size_t)r * OO * FF + col * FF + grp * 8;
        const unsigned short* hp = hfin4 + (size_t)r * NN * FF + (size_t)(n0 + col) * FF + grp * 8;
#pragma unroll
        for (int kt = 0; kt < 4; ++kt) {
            s16x8 ah = *(const s16x8*)(hp + kt * 32);
#pragma unroll
            for (int t = 0; t < 8; ++t) {
                s16x8 b1 = *(const s16x8*)(wsb + t * 16 * FF + kt * 32);
                acc[t] = __builtin_amdgcn_mfma_f32_16x16x32_bf16(af[kt], b1, acc[t], 0, 0, 0);
                s16x8 b2 = *(const s16x8*)(wnb + t * 16 * FF + kt * 32);
                acc[t] = __builtin_amdgcn_mfma_f32_16x16x32_bf16(ah, b2, acc[t], 0, 0, 0);
            }
        }
#pragma unroll
        for (int t = 0; t < 8; ++t) {
            if (r == 0)      m01[t] = acc[t];
            else if (r == 1) { m01[t][0] = fmaxf(m01[t][0], acc[t][0]); m01[t][1] = fmaxf(m01[t][1], acc[t][1]);
                               m01[t][2] = fmaxf(m01[t][2], acc[t][2]); m01[t][3] = fmaxf(m01[t][3], acc[t][3]); }
            else if (r == 2) m23[t] = acc[t];
            else             { m23[t][0] = fmaxf(m23[t][0], acc[t][0]); m23[t][1] = fmaxf(m23[t][1], acc[t][1]);
                               m23[t][2] = fmaxf(m23[t][2], acc[t][2]); m23[t][3] = fmaxf(m23[t][3], acc[t][3]); }
        }
    }
#pragma unroll
    for (int q = 0; q < 4; ++q) {
        int node = n0 + grp * 4 + q;
        int sg = seg[node];
#pragma unroll
        for (int t = 0; t < 8; ++t) {
            int idx = node * OO + t * 16 + col;
            out[idx] = mean[sg * FF + t * 16 + col] + m01[t][q] + m23[t][q];
        }
    }
}

extern "C" void kernel_launch(void* const* d_in, const int* in_sizes, int n_in,
                              void* d_out, int out_size, void* d_ws, size_t ws_size,
                              hipStream_t stream) {
    const float* feat = (const float*)d_in[0];
    const int* nbr[4] = {(const int*)d_in[1], (const int*)d_in[3], (const int*)d_in[5], (const int*)d_in[7]};
    const int* dgp[4] = {(const int*)d_in[2], (const int*)d_in[4], (const int*)d_in[6], (const int*)d_in[8]};
    const int* seg   = (const int*)d_in[9];
    const float* Wih = (const float*)d_in[10];
    const float* Whh = (const float*)d_in[11];
    const float* lb  = (const float*)d_in[12];
    const float* Ws  = (const float*)d_in[13];
    const float* Wn  = (const float*)d_in[14];
    const float* bo  = (const float*)d_in[15];

    char* ws = (char*)d_ws;
    float*          mean  = (float*)(ws + 0);                      //     32,768
    unsigned short* fbf   = (unsigned short*)(ws + 32768);         // 10,240,000
    unsigned short* wihb  = (unsigned short*)(ws + 10272768);      //    524,288
    unsigned short* whhb  = (unsigned short*)(ws + 10797056);      //    524,288
    unsigned short* wstb  = (unsigned short*)(ws + 11321344);      //    131,072
    unsigned short* wntb  = (unsigned short*)(ws + 11452416);      //    131,072
    unsigned short* hfin4 = (unsigned short*)(ws + 11583488);      // 40,960,000 (4 slices)
    int*            order4= (int*)(ws + 52543488);                 //    655,360
    int*            cnt4  = (int*)(ws + 53198848);                 //      1,024

    hipMemsetAsync(order4, 0xFF, 655360, stream);
    hipMemsetAsync(cnt4, 0, 1024, stream);
    hipMemsetAsync(hfin4, 0, 40960000, stream);

    k_prep<<<256, 256, 0, stream>>>(Wih, Whh, Ws, Wn, wihb, whhb, wstb, wntb);
    k_castfeat<<<5000, 256, 0, stream>>>(feat, fbf);
    k_segmean<<<64, 256, 0, stream>>>(feat, seg, mean);
    k_count<<<dim3(157, 4), 256, 0, stream>>>(dgp[0], dgp[1], dgp[2], dgp[3], cnt4);
    k_offsets<<<1, 64, 0, stream>>>(cnt4);
    k_scatter<<<dim3(157, 4), 256, 0, stream>>>(dgp[0], dgp[1], dgp[2], dgp[3], cnt4, order4);

    k_lstm<<<dim3(1280, 4), 256, 0, stream>>>(fbf, wihb, whhb, lb, order4,
                                              nbr[0], nbr[1], nbr[2], nbr[3],
                                              dgp[0], dgp[1], dgp[2], dgp[3], hfin4);
    k_proj<<<625, 256, 0, stream>>>(fbf, hfin4, wstb, wntb, bo, mean, seg, (float*)d_out);
}

// Round 5
// 922.919 us; speedup vs baseline: 2.4050x; 2.4050x over previous
//
#include <hip/hip_runtime.h>

#define NN 40000
#define DDEG 16
#define FF 128
#define OO 128
#define NG 512   // 4*F gates

typedef short  s16x8 __attribute__((ext_vector_type(8)));
typedef unsigned short u16x8 __attribute__((ext_vector_type(8)));
typedef float  f32x4 __attribute__((ext_vector_type(4)));

static_assert(sizeof(s16x8) == 16, "frag size");

__device__ __forceinline__ unsigned short f2bf(float f) {
    unsigned int u = __builtin_bit_cast(unsigned int, f);
    u += 0x7FFFu + ((u >> 16) & 1u);   // RNE
    return (unsigned short)(u >> 16);
}
__device__ __forceinline__ float bf2f(unsigned short s) {
    unsigned int u = ((unsigned int)s) << 16;
    return __builtin_bit_cast(float, u);
}
__device__ __forceinline__ float sigm(float x) {
    return __builtin_amdgcn_rcpf(1.0f + __expf(-x));
}
__device__ __forceinline__ float tanh_(float x) {
    float e = __expf(2.0f * x);
    return (e - 1.0f) * __builtin_amdgcn_rcpf(e + 1.0f);
}
__device__ __forceinline__ f32x4 splat4(float v) { f32x4 r = {v, v, v, v}; return r; }

// ---------------- prep: cast weights to bf16 (+ transpose Ws/Wn to [o][k]) ----
__global__ void k_prep(const float* __restrict__ Wih, const float* __restrict__ Whh,
                       const float* __restrict__ Ws,  const float* __restrict__ Wn,
                       unsigned short* __restrict__ wihb, unsigned short* __restrict__ whhb,
                       unsigned short* __restrict__ wstb, unsigned short* __restrict__ wntb) {
    int i = blockIdx.x * blockDim.x + threadIdx.x;
    int stride = gridDim.x * blockDim.x;
    for (int idx = i; idx < 4 * NG * FF; idx += stride) {
        wihb[idx] = f2bf(Wih[idx]);
        whhb[idx] = f2bf(Whh[idx]);
    }
    for (int idx = i; idx < 4 * FF * OO; idx += stride) {
        int r = idx >> 14;          // /(128*128)
        int rem = idx & 16383;
        int o = rem >> 7;
        int k = rem & 127;
        // dest [r][o][k] <- src [r][k][o]
        wstb[idx] = f2bf(Ws[(r << 14) + (k << 7) + o]);
        wntb[idx] = f2bf(Wn[(r << 14) + (k << 7) + o]);
    }
}

// ---------------- cast feat to bf16 ------------------------------------------
__global__ void k_castfeat(const float* __restrict__ feat, unsigned short* __restrict__ fbf) {
    int i = blockIdx.x * blockDim.x + threadIdx.x;
    int idx = i * 4;
    if (idx < NN * FF) {
        float4 v = *(const float4*)(feat + idx);
        ushort4 o;
        o.x = f2bf(v.x); o.y = f2bf(v.y); o.z = f2bf(v.z); o.w = f2bf(v.w);
        *(ushort4*)(fbf + idx) = o;
    }
}

// ---------------- segment mean (seg_ids sorted, G=64), float4 vectorized -----
__global__ void k_segmean(const float* __restrict__ feat, const int* __restrict__ seg,
                          float* __restrict__ mean) {
    int g = blockIdx.x;
    int lo, hi;
    { int a = 0, b = NN; while (a < b) { int m = (a + b) >> 1; if (seg[m] < g) a = m + 1; else b = m; } lo = a; }
    { int a = 0, b = NN; while (a < b) { int m = (a + b) >> 1; if (seg[m] < g + 1) a = m + 1; else b = m; } hi = a; }
    int tid = threadIdx.x;
    int d4 = tid & 31;          // float4 slot: dims [d4*4, d4*4+4)
    int part = tid >> 5;        // 8 row-partitions
    float4 s = {0.f, 0.f, 0.f, 0.f};
    for (int row = lo + part; row < hi; row += 8) {
        float4 v = *(const float4*)(feat + (size_t)row * FF + d4 * 4);
        s.x += v.x; s.y += v.y; s.z += v.z; s.w += v.w;
    }
    __shared__ float ps[8][128];
    ps[part][d4 * 4 + 0] = s.x; ps[part][d4 * 4 + 1] = s.y;
    ps[part][d4 * 4 + 2] = s.z; ps[part][d4 * 4 + 3] = s.w;
    __syncthreads();
    if (tid < 128) {
        float tot = 0.f;
#pragma unroll
        for (int p = 0; p < 8; ++p) tot += ps[p][tid];
        mean[g * FF + tid] = tot / fmaxf((float)(hi - lo), 1.0f);
    }
}

// ---------------- deg bucketing, all 4 relations -----------------------------
// cnt4[r*64 + d] = counts (d=1..16), cnt4[r*64 + 40 + d] = cursor
__global__ void k_count(const int* __restrict__ D0, const int* __restrict__ D1,
                        const int* __restrict__ D2, const int* __restrict__ D3,
                        int* __restrict__ cnt4) {
    int r = blockIdx.y;
    const int* dg = (r == 0) ? D0 : (r == 1) ? D1 : (r == 2) ? D2 : D3;
    int n = blockIdx.x * blockDim.x + threadIdx.x;
    if (n < NN) { int d = dg[n]; if (d > 0) atomicAdd(&cnt4[r * 64 + d], 1); }
}
__global__ void k_offsets(int* __restrict__ cnt4) {
    int r = threadIdx.x;
    if (r < 4 && blockIdx.x == 0) {
        int running = 0;
        for (int d = 16; d >= 1; --d) {             // heavy buckets first
            cnt4[r * 64 + 40 + d] = running;
            running += (cnt4[r * 64 + d] + 15) & ~15;   // pad each bucket to x16
        }
    }
}
__global__ void k_scatter(const int* __restrict__ D0, const int* __restrict__ D1,
                          const int* __restrict__ D2, const int* __restrict__ D3,
                          int* __restrict__ cnt4, int* __restrict__ order4) {
    int r = blockIdx.y;
    const int* dg = (r == 0) ? D0 : (r == 1) ? D1 : (r == 2) ? D2 : D3;
    int n = blockIdx.x * blockDim.x + threadIdx.x;
    if (n < NN) {
        int d = dg[n];
        if (d > 0) { int p = atomicAdd(&cnt4[r * 64 + 40 + d], 1); order4[r * 40960 + p] = n; }
    }
}

// ---------------- Xih = feat @ Wih[r].T + b, wave-permuted storage ----------
// Wave w owns gate-tiles {w+4j : j=0..7}. Row layout (512 u16 = 1KB):
// u16 index w*128 + col*8 + j  holds gate (w+4j)*16+col.
__global__ __launch_bounds__(256, 4) void k_xih(const unsigned short* __restrict__ fbf,
                                                const unsigned short* __restrict__ wihb,
                                                const float* __restrict__ lb,
                                                unsigned short* __restrict__ xih, int r) {
    int tid = threadIdx.x;
    int w = tid >> 6;
    int l = tid & 63;
    int n0 = blockIdx.x * 16;
    int col = l & 15, grp = l >> 4;

    f32x4 acc[8];
#pragma unroll
    for (int j = 0; j < 8; ++j) acc[j] = splat4(lb[r * NG + (w + 4 * j) * 16 + col]);

    s16x8 a[4];
    const unsigned short* ap = fbf + (size_t)(n0 + col) * FF + grp * 8;
#pragma unroll
    for (int kt = 0; kt < 4; ++kt) a[kt] = *(const s16x8*)(ap + kt * 32);

    const unsigned short* wb = wihb + (size_t)r * NG * FF + col * FF + grp * 8;
#pragma unroll
    for (int j = 0; j < 8; ++j) {
#pragma unroll
        for (int kt = 0; kt < 4; ++kt) {
            s16x8 b = *(const s16x8*)(wb + (size_t)(w + 4 * j) * 16 * FF + kt * 32);
            acc[j] = __builtin_amdgcn_mfma_f32_16x16x32_bf16(a[kt], b, acc[j], 0, 0, 0);
        }
    }
#pragma unroll
    for (int q = 0; q < 4; ++q) {
        u16x8 hv;
#pragma unroll
        for (int j = 0; j < 8; ++j) hv[j] = f2bf(acc[j][q]);
        *(u16x8*)(xih + (size_t)(n0 + grp * 4 + q) * NG + w * 128 + col * 8) = hv;
    }
}

// ---------------- bucketed LSTM, Whh resident in REGISTERS -------------------
// 256 thr = 4 waves; block owns 16 nodes of equal deg. Wave w owns tiles
// {w+4j}; its Whh slice = 32 s16x8 frags = 128 VGPRs, loaded ONCE before the
// loop. Per step: 4 prefetched gathers + 4 LDS h-reads + 32 MFMA + in-register
// activations; h via double-buffered swizzled LDS; ONE barrier per step.
__global__ __launch_bounds__(256, 2) void k_lstm(const unsigned short* __restrict__ xih,
                                                 const unsigned short* __restrict__ whhb,
                                                 const int* __restrict__ order,
                                                 const int* __restrict__ nbr,
                                                 const int* __restrict__ deg,
                                                 unsigned short* __restrict__ hfin, int r) {
    __shared__ int nodes[16];
    __shared__ int nbrs[16][16];
    __shared__ unsigned short hbuf[2][2048];   // 2 x (16 rows x 128 dims bf16), XOR-swizzled
    int tid = threadIdx.x;
    int w = tid >> 6, l = tid & 63;
    int g0 = blockIdx.x * 16;
    if (tid < 16) nodes[tid] = order[g0 + tid];
    __syncthreads();
    if (nodes[0] < 0) return;
    int degv = deg[nodes[0]];

    {
        int row = tid >> 4, t = tid & 15;
        int nd = nodes[row]; if (nd < 0) nd = 0;
        nbrs[row][t] = nbr[nd * DDEG + t];
    }
    __syncthreads();

    int col = l & 15, grp = l >> 4;

    // hoist this wave's entire Whh slice into registers (loop-invariant)
    const unsigned short* whhp = whhb + (size_t)r * NG * FF + col * FF + grp * 8;
    s16x8 breg[8][4];
#pragma unroll
    for (int j = 0; j < 8; ++j)
#pragma unroll
        for (int kt = 0; kt < 4; ++kt)
            breg[j][kt] = *(const s16x8*)(whhp + (size_t)(w + 4 * j) * 16 * FF + kt * 32);

    const unsigned short* xb = xih + w * 128 + col * 8;

    float cst[8];
#pragma unroll
    for (int e = 0; e < 8; ++e) cst[e] = 0.f;

    // prefetch gathers for t=0
    u16x8 cur[4], nxt[4];
#pragma unroll
    for (int q = 0; q < 4; ++q) {
        cur[q] = *(const u16x8*)(xb + (size_t)nbrs[grp * 4 + q][0] * NG);
        nxt[q] = cur[q];
    }

    for (int t = 0; t < degv; ++t) {
        // issue next-step gathers early (overlap with MFMA + activations)
        if (t + 1 < degv) {
#pragma unroll
            for (int q = 0; q < 4; ++q)
                nxt[q] = *(const u16x8*)(xb + (size_t)nbrs[grp * 4 + q][t + 1] * NG);
        }
        f32x4 acc[8];
#pragma unroll
        for (int j = 0; j < 8; ++j)
#pragma unroll
            for (int q = 0; q < 4; ++q)
                acc[j][q] = bf2f(cur[q][j]);

        if (t > 0) {
            const char* hrd = (const char*)hbuf[t & 1];
            s16x8 ah[4];
#pragma unroll
            for (int kt = 0; kt < 4; ++kt) {
                int byte = (col * 256 + kt * 64 + grp * 16) ^ ((col & 7) << 4);
                ah[kt] = *(const s16x8*)(hrd + byte);
            }
#pragma unroll
            for (int j = 0; j < 8; ++j)
#pragma unroll
                for (int kt = 0; kt < 4; ++kt)
                    acc[j] = __builtin_amdgcn_mfma_f32_16x16x32_bf16(ah[kt], breg[j][kt], acc[j], 0, 0, 0);
        }
        // in-register activations; write h to the other buffer
        char* hwr = (char*)hbuf[(t + 1) & 1];
#pragma unroll
        for (int ji = 0; ji < 2; ++ji) {
#pragma unroll
            for (int q = 0; q < 4; ++q) {
                float iv = sigm(acc[ji][q]);
                float fv = sigm(acc[ji + 2][q]);
                float gv = tanh_(acc[ji + 4][q]);
                float ov = sigm(acc[ji + 6][q]);
                int ci = ji * 4 + q;
                float cv = fv * cst[ci] + iv * gv;
                cst[ci] = cv;
                float hv = ov * tanh_(cv);
                int node = grp * 4 + q;
                int dim = (w + 4 * ji) * 16 + col;
                int byte = (node * 256 + dim * 2) ^ ((node & 7) << 4);
                *(unsigned short*)(hwr + byte) = f2bf(hv);
            }
        }
#pragma unroll
        for (int q = 0; q < 4; ++q) cur[q] = nxt[q];
        __syncthreads();
    }
    // write h_fin from hbuf[degv & 1]
    const char* hf = (const char*)hbuf[degv & 1];
    int row = tid >> 4;
    int nd = nodes[row];
    if (nd >= 0) {
        int off = (tid & 15) * 16;                    // byte within row
        int byte = (row * 256 + off) ^ ((row & 7) << 4);
        u16x8 v = *(const u16x8*)(hf + byte);
        *(u16x8*)(hfin + (size_t)nd * FF + off / 2) = v;
    }
}

// ---------------- fused projection: all 4 r + max/add + residual -------------
__global__ __launch_bounds__(256, 2) void k_proj(const unsigned short* __restrict__ fbf,
                                                 const unsigned short* __restrict__ hfin4,
                                                 const unsigned short* __restrict__ wstb,
                                                 const unsigned short* __restrict__ wntb,
                                                 const float* __restrict__ bo,
                                                 const float* __restrict__ mean,
                                                 const int* __restrict__ seg,
                                                 float* __restrict__ out) {
    int wv = threadIdx.x >> 6, l = threadIdx.x & 63;
    int n0 = blockIdx.x * 64 + wv * 16;
    int col = l & 15, grp = l >> 4;

    s16x8 af[4];
    const unsigned short* fp = fbf + (size_t)(n0 + col) * FF + grp * 8;
#pragma unroll
    for (int kt = 0; kt < 4; ++kt) af[kt] = *(const s16x8*)(fp + kt * 32);

    f32x4 m01[8], m23[8];
#pragma unroll
    for (int r = 0; r < 4; ++r) {
        f32x4 acc[8];
#pragma unroll
        for (int t = 0; t < 8; ++t) acc[t] = splat4(bo[r * OO + t * 16 + col]);

        const unsigned short* wsb = wstb + (size_t)r * OO * FF + col * FF + grp * 8;
        const unsigned short* wnb = wntb + (size_t)r * OO * FF + col * FF + grp * 8;
        const unsigned short* hp = hfin4 + (size_t)r * NN * FF + (size_t)(n0 + col) * FF + grp * 8;
#pragma unroll
        for (int kt = 0; kt < 4; ++kt) {
            s16x8 ah = *(const s16x8*)(hp + kt * 32);
#pragma unroll
            for (int t = 0; t < 8; ++t) {
                s16x8 b1 = *(const s16x8*)(wsb + t * 16 * FF + kt * 32);
                acc[t] = __builtin_amdgcn_mfma_f32_16x16x32_bf16(af[kt], b1, acc[t], 0, 0, 0);
                s16x8 b2 = *(const s16x8*)(wnb + t * 16 * FF + kt * 32);
                acc[t] = __builtin_amdgcn_mfma_f32_16x16x32_bf16(ah, b2, acc[t], 0, 0, 0);
            }
        }
#pragma unroll
        for (int t = 0; t < 8; ++t) {
            if (r == 0)      m01[t] = acc[t];
            else if (r == 1) { m01[t][0] = fmaxf(m01[t][0], acc[t][0]); m01[t][1] = fmaxf(m01[t][1], acc[t][1]);
                               m01[t][2] = fmaxf(m01[t][2], acc[t][2]); m01[t][3] = fmaxf(m01[t][3], acc[t][3]); }
            else if (r == 2) m23[t] = acc[t];
            else             { m23[t][0] = fmaxf(m23[t][0], acc[t][0]); m23[t][1] = fmaxf(m23[t][1], acc[t][1]);
                               m23[t][2] = fmaxf(m23[t][2], acc[t][2]); m23[t][3] = fmaxf(m23[t][3], acc[t][3]); }
        }
    }
#pragma unroll
    for (int q = 0; q < 4; ++q) {
        int node = n0 + grp * 4 + q;
        int sg = seg[node];
#pragma unroll
        for (int t = 0; t < 8; ++t) {
            int idx = node * OO + t * 16 + col;
            out[idx] = mean[sg * FF + t * 16 + col] + m01[t][q] + m23[t][q];
        }
    }
}

extern "C" void kernel_launch(void* const* d_in, const int* in_sizes, int n_in,
                              void* d_out, int out_size, void* d_ws, size_t ws_size,
                              hipStream_t stream) {
    const float* feat = (const float*)d_in[0];
    const int* nbr[4] = {(const int*)d_in[1], (const int*)d_in[3], (const int*)d_in[5], (const int*)d_in[7]};
    const int* dgp[4] = {(const int*)d_in[2], (const int*)d_in[4], (const int*)d_in[6], (const int*)d_in[8]};
    const int* seg   = (const int*)d_in[9];
    const float* Wih = (const float*)d_in[10];
    const float* Whh = (const float*)d_in[11];
    const float* lb  = (const float*)d_in[12];
    const float* Ws  = (const float*)d_in[13];
    const float* Wn  = (const float*)d_in[14];
    const float* bo  = (const float*)d_in[15];

    char* ws = (char*)d_ws;
    float*          mean  = (float*)(ws + 0);                      //     32,768
    unsigned short* fbf   = (unsigned short*)(ws + 32768);         // 10,240,000
    unsigned short* wihb  = (unsigned short*)(ws + 10272768);      //    524,288
    unsigned short* whhb  = (unsigned short*)(ws + 10797056);      //    524,288
    unsigned short* wstb  = (unsigned short*)(ws + 11321344);      //    131,072
    unsigned short* wntb  = (unsigned short*)(ws + 11452416);      //    131,072
    unsigned short* xih   = (unsigned short*)(ws + 11583488);      // 40,960,000
    unsigned short* hfin4 = (unsigned short*)(ws + 52543488);      // 40,960,000 (4 slices)
    int*            order4= (int*)(ws + 93503488);                 //    655,360
    int*            cnt4  = (int*)(ws + 94158848);                 //      1,024

    hipMemsetAsync(order4, 0xFF, 655360, stream);
    hipMemsetAsync(cnt4, 0, 1024, stream);
    hipMemsetAsync(hfin4, 0, 40960000, stream);

    k_prep<<<256, 256, 0, stream>>>(Wih, Whh, Ws, Wn, wihb, whhb, wstb, wntb);
    k_castfeat<<<5000, 256, 0, stream>>>(feat, fbf);
    k_segmean<<<64, 256, 0, stream>>>(feat, seg, mean);
    k_count<<<dim3(157, 4), 256, 0, stream>>>(dgp[0], dgp[1], dgp[2], dgp[3], cnt4);
    k_offsets<<<1, 64, 0, stream>>>(cnt4);
    k_scatter<<<dim3(157, 4), 256, 0, stream>>>(dgp[0], dgp[1], dgp[2], dgp[3], cnt4, order4);

    for (int r = 0; r < 4; ++r) {
        k_xih<<<2500, 256, 0, stream>>>(fbf, wihb, lb, xih, r);
        k_lstm<<<2560, 256, 0, stream>>>(xih, whhb, order4 + r * 40960, nbr[r], dgp[r],
                                         hfin4 + (size_t)r * NN * FF, r);
    }
    k_proj<<<625, 256, 0, stream>>>(fbf, hfin4, wstb, wntb, bo, mean, seg, (float*)d_out);
}

// Round 6
// 725.716 us; speedup vs baseline: 3.0586x; 1.2717x over previous
//
#include <hip/hip_runtime.h>

#define NN 40000
#define DDEG 16
#define FF 128
#define OO 128
#define NG 512   // 4*F gates

typedef short  s16x8 __attribute__((ext_vector_type(8)));
typedef unsigned short u16x8 __attribute__((ext_vector_type(8)));
typedef float  f32x4 __attribute__((ext_vector_type(4)));

static_assert(sizeof(s16x8) == 16, "frag size");

__device__ __forceinline__ unsigned short f2bf(float f) {
    unsigned int u = __builtin_bit_cast(unsigned int, f);
    u += 0x7FFFu + ((u >> 16) & 1u);   // RNE
    return (unsigned short)(u >> 16);
}
__device__ __forceinline__ float bf2f(unsigned short s) {
    unsigned int u = ((unsigned int)s) << 16;
    return __builtin_bit_cast(float, u);
}
__device__ __forceinline__ float sigm(float x) {
    return __builtin_amdgcn_rcpf(1.0f + __expf(-x));
}
__device__ __forceinline__ float tanh_(float x) {
    float e = __expf(2.0f * x);
    return (e - 1.0f) * __builtin_amdgcn_rcpf(e + 1.0f);
}
__device__ __forceinline__ f32x4 splat4(float v) { f32x4 r = {v, v, v, v}; return r; }

// ---------------- prep: cast weights to bf16 (+ transpose Ws/Wn to [o][k]) ----
__global__ void k_prep(const float* __restrict__ Wih, const float* __restrict__ Whh,
                       const float* __restrict__ Ws,  const float* __restrict__ Wn,
                       unsigned short* __restrict__ wihb, unsigned short* __restrict__ whhb,
                       unsigned short* __restrict__ wstb, unsigned short* __restrict__ wntb) {
    int i = blockIdx.x * blockDim.x + threadIdx.x;
    int stride = gridDim.x * blockDim.x;
    for (int idx = i; idx < 4 * NG * FF; idx += stride) {
        wihb[idx] = f2bf(Wih[idx]);
        whhb[idx] = f2bf(Whh[idx]);
    }
    for (int idx = i; idx < 4 * FF * OO; idx += stride) {
        int r = idx >> 14;          // /(128*128)
        int rem = idx & 16383;
        int o = rem >> 7;
        int k = rem & 127;
        // dest [r][o][k] <- src [r][k][o]
        wstb[idx] = f2bf(Ws[(r << 14) + (k << 7) + o]);
        wntb[idx] = f2bf(Wn[(r << 14) + (k << 7) + o]);
    }
}

// ---------------- cast feat to bf16 ------------------------------------------
__global__ void k_castfeat(const float* __restrict__ feat, unsigned short* __restrict__ fbf) {
    int i = blockIdx.x * blockDim.x + threadIdx.x;
    int idx = i * 4;
    if (idx < NN * FF) {
        float4 v = *(const float4*)(feat + idx);
        ushort4 o;
        o.x = f2bf(v.x); o.y = f2bf(v.y); o.z = f2bf(v.z); o.w = f2bf(v.w);
        *(ushort4*)(fbf + idx) = o;
    }
}

// ---------------- segment mean (seg_ids sorted, G=64), float4 vectorized -----
__global__ void k_segmean(const float* __restrict__ feat, const int* __restrict__ seg,
                          float* __restrict__ mean) {
    int g = blockIdx.x;
    int lo, hi;
    { int a = 0, b = NN; while (a < b) { int m = (a + b) >> 1; if (seg[m] < g) a = m + 1; else b = m; } lo = a; }
    { int a = 0, b = NN; while (a < b) { int m = (a + b) >> 1; if (seg[m] < g + 1) a = m + 1; else b = m; } hi = a; }
    int tid = threadIdx.x;
    int d4 = tid & 31;          // float4 slot: dims [d4*4, d4*4+4)
    int part = tid >> 5;        // 8 row-partitions
    float4 s = {0.f, 0.f, 0.f, 0.f};
    for (int row = lo + part; row < hi; row += 8) {
        float4 v = *(const float4*)(feat + (size_t)row * FF + d4 * 4);
        s.x += v.x; s.y += v.y; s.z += v.z; s.w += v.w;
    }
    __shared__ float ps[8][128];
    ps[part][d4 * 4 + 0] = s.x; ps[part][d4 * 4 + 1] = s.y;
    ps[part][d4 * 4 + 2] = s.z; ps[part][d4 * 4 + 3] = s.w;
    __syncthreads();
    if (tid < 128) {
        float tot = 0.f;
#pragma unroll
        for (int p = 0; p < 8; ++p) tot += ps[p][tid];
        mean[g * FF + tid] = tot / fmaxf((float)(hi - lo), 1.0f);
    }
}

// ---------------- deg bucketing, all 4 relations (two-level histogram) -------
// cnt4[r*64 + d] = counts (d=1..16), cnt4[r*64 + 40 + d] = cursor
__global__ void k_count(const int* __restrict__ D0, const int* __restrict__ D1,
                        const int* __restrict__ D2, const int* __restrict__ D3,
                        int* __restrict__ cnt4) {
    int r = blockIdx.y;
    const int* dg = (r == 0) ? D0 : (r == 1) ? D1 : (r == 2) ? D2 : D3;
    __shared__ int lcnt[17];
    if (threadIdx.x < 17) lcnt[threadIdx.x] = 0;
    __syncthreads();
    int n = blockIdx.x * blockDim.x + threadIdx.x;
    if (n < NN) { int d = dg[n]; if (d > 0) atomicAdd(&lcnt[d], 1); }
    __syncthreads();
    if (threadIdx.x >= 1 && threadIdx.x < 17 && lcnt[threadIdx.x])
        atomicAdd(&cnt4[r * 64 + threadIdx.x], lcnt[threadIdx.x]);
}
__global__ void k_offsets(int* __restrict__ cnt4) {
    int r = threadIdx.x;
    if (r < 4 && blockIdx.x == 0) {
        int running = 0;
        for (int d = 16; d >= 1; --d) {             // heavy buckets first
            cnt4[r * 64 + 40 + d] = running;
            running += (cnt4[r * 64 + d] + 15) & ~15;   // pad each bucket to x16
        }
    }
}
__global__ void k_scatter(const int* __restrict__ D0, const int* __restrict__ D1,
                          const int* __restrict__ D2, const int* __restrict__ D3,
                          int* __restrict__ cnt4, int* __restrict__ order4) {
    int r = blockIdx.y;
    const int* dg = (r == 0) ? D0 : (r == 1) ? D1 : (r == 2) ? D2 : D3;
    __shared__ int lcnt[17];
    __shared__ int gbase[17];
    if (threadIdx.x < 17) lcnt[threadIdx.x] = 0;
    __syncthreads();
    int n = blockIdx.x * blockDim.x + threadIdx.x;
    int d = 0, rank = 0;
    if (n < NN) { d = dg[n]; if (d > 0) rank = atomicAdd(&lcnt[d], 1); }
    __syncthreads();
    if (threadIdx.x >= 1 && threadIdx.x < 17 && lcnt[threadIdx.x])
        gbase[threadIdx.x] = atomicAdd(&cnt4[r * 64 + 40 + threadIdx.x], lcnt[threadIdx.x]);
    __syncthreads();
    if (n < NN && d > 0) order4[r * 40960 + gbase[d] + rank] = n;
}

// ---------------- Xih = feat @ Wih[r].T + b, wave-permuted storage ----------
// Wave w owns gate-tiles {w+4j : j=0..7}. Row layout (512 u16 = 1KB):
// u16 index w*128 + col*8 + j  holds gate (w+4j)*16+col.
__global__ __launch_bounds__(256, 4) void k_xih(const unsigned short* __restrict__ fbf,
                                                const unsigned short* __restrict__ wihb,
                                                const float* __restrict__ lb,
                                                unsigned short* __restrict__ xih, int r) {
    int tid = threadIdx.x;
    int w = tid >> 6;
    int l = tid & 63;
    int n0 = blockIdx.x * 16;
    int col = l & 15, grp = l >> 4;

    f32x4 acc[8];
#pragma unroll
    for (int j = 0; j < 8; ++j) acc[j] = splat4(lb[r * NG + (w + 4 * j) * 16 + col]);

    s16x8 a[4];
    const unsigned short* ap = fbf + (size_t)(n0 + col) * FF + grp * 8;
#pragma unroll
    for (int kt = 0; kt < 4; ++kt) a[kt] = *(const s16x8*)(ap + kt * 32);

    const unsigned short* wb = wihb + (size_t)r * NG * FF + col * FF + grp * 8;
#pragma unroll
    for (int j = 0; j < 8; ++j) {
#pragma unroll
        for (int kt = 0; kt < 4; ++kt) {
            s16x8 b = *(const s16x8*)(wb + (size_t)(w + 4 * j) * 16 * FF + kt * 32);
            acc[j] = __builtin_amdgcn_mfma_f32_16x16x32_bf16(a[kt], b, acc[j], 0, 0, 0);
        }
    }
#pragma unroll
    for (int q = 0; q < 4; ++q) {
        u16x8 hv;
#pragma unroll
        for (int j = 0; j < 8; ++j) hv[j] = f2bf(acc[j][q]);
        *(u16x8*)(xih + (size_t)(n0 + grp * 4 + q) * NG + w * 128 + col * 8) = hv;
    }
}

// ---------------- bucketed LSTM, Whh in registers, persistent over 4 groups --
// 256 thr = 4 waves; block processes 4 strided groups of 16 equal-deg nodes.
// Wave w owns tiles {w+4j}; Whh slice = 32 s16x8 = 128 VGPRs loaded ONCE per
// block. Per step: 4 prefetched gathers + 4 LDS h-reads + 32 MFMA + in-register
// activations; h via double-buffered swizzled LDS; ONE barrier per step.
#define LSTM_BLOCKS 640
__global__ __launch_bounds__(256, 2) void k_lstm(const unsigned short* __restrict__ xih,
                                                 const unsigned short* __restrict__ whhb,
                                                 const int* __restrict__ order,
                                                 const int* __restrict__ nbr,
                                                 const int* __restrict__ deg,
                                                 unsigned short* __restrict__ hfin, int r) {
    __shared__ int nodes[16];
    __shared__ int nbrs[16][16];
    __shared__ unsigned short hbuf[2][2048];   // 2 x (16 rows x 128 dims bf16), XOR-swizzled
    int tid = threadIdx.x;
    int w = tid >> 6, l = tid & 63;
    int col = l & 15, grp = l >> 4;

    // hoist this wave's entire Whh slice into registers (invariant across groups)
    const unsigned short* whhp = whhb + (size_t)r * NG * FF + col * FF + grp * 8;
    s16x8 breg[8][4];
#pragma unroll
    for (int j = 0; j < 8; ++j)
#pragma unroll
        for (int kt = 0; kt < 4; ++kt)
            breg[j][kt] = *(const s16x8*)(whhp + (size_t)(w + 4 * j) * 16 * FF + kt * 32);

    const unsigned short* xb = xih + w * 128 + col * 8;

    for (int gi = 0; gi < 4; ++gi) {
        int g0 = (blockIdx.x + gi * LSTM_BLOCKS) * 16;
        __syncthreads();   // prior group's reads of nodes/nbrs/hbuf complete
        if (tid < 16) nodes[tid] = order[g0 + tid];
        __syncthreads();
        if (nodes[0] < 0) continue;          // uniform across block
        int degv = deg[nodes[0]];

        {
            int row = tid >> 4, t = tid & 15;
            int nd = nodes[row]; if (nd < 0) nd = 0;
            nbrs[row][t] = nbr[nd * DDEG + t];
        }
        __syncthreads();

        float cst[8];
#pragma unroll
        for (int e = 0; e < 8; ++e) cst[e] = 0.f;

        // prefetch gathers for t=0
        u16x8 cur[4], nxt[4];
#pragma unroll
        for (int q = 0; q < 4; ++q) {
            cur[q] = *(const u16x8*)(xb + (size_t)nbrs[grp * 4 + q][0] * NG);
            nxt[q] = cur[q];
        }

        for (int t = 0; t < degv; ++t) {
            // issue next-step gathers early (overlap with MFMA + activations)
            if (t + 1 < degv) {
#pragma unroll
                for (int q = 0; q < 4; ++q)
                    nxt[q] = *(const u16x8*)(xb + (size_t)nbrs[grp * 4 + q][t + 1] * NG);
            }
            f32x4 acc[8];
#pragma unroll
            for (int j = 0; j < 8; ++j)
#pragma unroll
                for (int q = 0; q < 4; ++q)
                    acc[j][q] = bf2f(cur[q][j]);

            if (t > 0) {
                const char* hrd = (const char*)hbuf[t & 1];
                s16x8 ah[4];
#pragma unroll
                for (int kt = 0; kt < 4; ++kt) {
                    int byte = (col * 256 + kt * 64 + grp * 16) ^ ((col & 7) << 4);
                    ah[kt] = *(const s16x8*)(hrd + byte);
                }
#pragma unroll
                for (int j = 0; j < 8; ++j)
#pragma unroll
                    for (int kt = 0; kt < 4; ++kt)
                        acc[j] = __builtin_amdgcn_mfma_f32_16x16x32_bf16(ah[kt], breg[j][kt], acc[j], 0, 0, 0);
            }
            // in-register activations; write h to the other buffer
            char* hwr = (char*)hbuf[(t + 1) & 1];
#pragma unroll
            for (int ji = 0; ji < 2; ++ji) {
#pragma unroll
                for (int q = 0; q < 4; ++q) {
                    float iv = sigm(acc[ji][q]);
                    float fv = sigm(acc[ji + 2][q]);
                    float gv = tanh_(acc[ji + 4][q]);
                    float ov = sigm(acc[ji + 6][q]);
                    int ci = ji * 4 + q;
                    float cv = fv * cst[ci] + iv * gv;
                    cst[ci] = cv;
                    float hv = ov * tanh_(cv);
                    int node = grp * 4 + q;
                    int dim = (w + 4 * ji) * 16 + col;
                    int byte = (node * 256 + dim * 2) ^ ((node & 7) << 4);
                    *(unsigned short*)(hwr + byte) = f2bf(hv);
                }
            }
#pragma unroll
            for (int q = 0; q < 4; ++q) cur[q] = nxt[q];
            __syncthreads();
        }
        // write h_fin from hbuf[degv & 1]
        const char* hf = (const char*)hbuf[degv & 1];
        int row = tid >> 4;
        int nd = nodes[row];
        if (nd >= 0) {
            int off = (tid & 15) * 16;                    // byte within row
            int byte = (row * 256 + off) ^ ((row & 7) << 4);
            u16x8 v = *(const u16x8*)(hf + byte);
            *(u16x8*)(hfin + (size_t)nd * FF + off / 2) = v;
        }
    }
}

// ---------------- fused projection: all 4 r + max/add + residual -------------
__global__ __launch_bounds__(256, 2) void k_proj(const unsigned short* __restrict__ fbf,
                                                 const unsigned short* __restrict__ hfin4,
                                                 const unsigned short* __restrict__ wstb,
                                                 const unsigned short* __restrict__ wntb,
                                                 const float* __restrict__ bo,
                                                 const float* __restrict__ mean,
                                                 const int* __restrict__ seg,
                                                 float* __restrict__ out) {
    int wv = threadIdx.x >> 6, l = threadIdx.x & 63;
    int n0 = blockIdx.x * 64 + wv * 16;
    int col = l & 15, grp = l >> 4;

    s16x8 af[4];
    const unsigned short* fp = fbf + (size_t)(n0 + col) * FF + grp * 8;
#pragma unroll
    for (int kt = 0; kt < 4; ++kt) af[kt] = *(const s16x8*)(fp + kt * 32);

    f32x4 m01[8], m23[8];
#pragma unroll
    for (int r = 0; r < 4; ++r) {
        f32x4 acc[8];
#pragma unroll
        for (int t = 0; t < 8; ++t) acc[t] = splat4(bo[r * OO + t * 16 + col]);

        const unsigned short* wsb = wstb + (size_t)r * OO * FF + col * FF + grp * 8;
        const unsigned short* wnb = wntb + (size_t)r * OO * FF + col * FF + grp * 8;
        const unsigned short* hp = hfin4 + (size_t)r * NN * FF + (size_t)(n0 + col) * FF + grp * 8;
#pragma unroll
        for (int kt = 0; kt < 4; ++kt) {
            s16x8 ah = *(const s16x8*)(hp + kt * 32);
#pragma unroll
            for (int t = 0; t < 8; ++t) {
                s16x8 b1 = *(const s16x8*)(wsb + t * 16 * FF + kt * 32);
                acc[t] = __builtin_amdgcn_mfma_f32_16x16x32_bf16(af[kt], b1, acc[t], 0, 0, 0);
                s16x8 b2 = *(const s16x8*)(wnb + t * 16 * FF + kt * 32);
                acc[t] = __builtin_amdgcn_mfma_f32_16x16x32_bf16(ah, b2, acc[t], 0, 0, 0);
            }
        }
#pragma unroll
        for (int t = 0; t < 8; ++t) {
            if (r == 0)      m01[t] = acc[t];
            else if (r == 1) { m01[t][0] = fmaxf(m01[t][0], acc[t][0]); m01[t][1] = fmaxf(m01[t][1], acc[t][1]);
                               m01[t][2] = fmaxf(m01[t][2], acc[t][2]); m01[t][3] = fmaxf(m01[t][3], acc[t][3]); }
            else if (r == 2) m23[t] = acc[t];
            else             { m23[t][0] = fmaxf(m23[t][0], acc[t][0]); m23[t][1] = fmaxf(m23[t][1], acc[t][1]);
                               m23[t][2] = fmaxf(m23[t][2], acc[t][2]); m23[t][3] = fmaxf(m23[t][3], acc[t][3]); }
        }
    }
#pragma unroll
    for (int q = 0; q < 4; ++q) {
        int node = n0 + grp * 4 + q;
        int sg = seg[node];
#pragma unroll
        for (int t = 0; t < 8; ++t) {
            int idx = node * OO + t * 16 + col;
            out[idx] = mean[sg * FF + t * 16 + col] + m01[t][q] + m23[t][q];
        }
    }
}

extern "C" void kernel_launch(void* const* d_in, const int* in_sizes, int n_in,
                              void* d_out, int out_size, void* d_ws, size_t ws_size,
                              hipStream_t stream) {
    const float* feat = (const float*)d_in[0];
    const int* nbr[4] = {(const int*)d_in[1], (const int*)d_in[3], (const int*)d_in[5], (const int*)d_in[7]};
    const int* dgp[4] = {(const int*)d_in[2], (const int*)d_in[4], (const int*)d_in[6], (const int*)d_in[8]};
    const int* seg   = (const int*)d_in[9];
    const float* Wih = (const float*)d_in[10];
    const float* Whh = (const float*)d_in[11];
    const float* lb  = (const float*)d_in[12];
    const float* Ws  = (const float*)d_in[13];
    const float* Wn  = (const float*)d_in[14];
    const float* bo  = (const float*)d_in[15];

    char* ws = (char*)d_ws;
    float*          mean  = (float*)(ws + 0);                      //     32,768
    unsigned short* fbf   = (unsigned short*)(ws + 32768);         // 10,240,000
    unsigned short* wihb  = (unsigned short*)(ws + 10272768);      //    524,288
    unsigned short* whhb  = (unsigned short*)(ws + 10797056);      //    524,288
    unsigned short* wstb  = (unsigned short*)(ws + 11321344);      //    131,072
    unsigned short* wntb  = (unsigned short*)(ws + 11452416);      //    131,072
    unsigned short* xih   = (unsigned short*)(ws + 11583488);      // 40,960,000
    unsigned short* hfin4 = (unsigned short*)(ws + 52543488);      // 40,960,000 (4 slices)
    int*            order4= (int*)(ws + 93503488);                 //    655,360
    int*            cnt4  = (int*)(ws + 94158848);                 //      1,024

    hipMemsetAsync(order4, 0xFF, 655360, stream);
    hipMemsetAsync(cnt4, 0, 1024, stream);
    hipMemsetAsync(hfin4, 0, 40960000, stream);

    k_prep<<<256, 256, 0, stream>>>(Wih, Whh, Ws, Wn, wihb, whhb, wstb, wntb);
    k_castfeat<<<5000, 256, 0, stream>>>(feat, fbf);
    k_segmean<<<64, 256, 0, stream>>>(feat, seg, mean);
    k_count<<<dim3(157, 4), 256, 0, stream>>>(dgp[0], dgp[1], dgp[2], dgp[3], cnt4);
    k_offsets<<<1, 64, 0, stream>>>(cnt4);
    k_scatter<<<dim3(157, 4), 256, 0, stream>>>(dgp[0], dgp[1], dgp[2], dgp[3], cnt4, order4);

    for (int r = 0; r < 4; ++r) {
        k_xih<<<2500, 256, 0, stream>>>(fbf, wihb, lb, xih, r);
        k_lstm<<<LSTM_BLOCKS, 256, 0, stream>>>(xih, whhb, order4 + r * 40960, nbr[r], dgp[r],
                                                hfin4 + (size_t)r * NN * FF, r);
    }
    k_proj<<<625, 256, 0, stream>>>(fbf, hfin4, wstb, wntb, bo, mean, seg, (float*)d_out);
}

// Round 7
// 648.379 us; speedup vs baseline: 3.4234x; 1.1193x over previous
//
#include <hip/hip_runtime.h>

#define NN 40000
#define DDEG 16
#define FF 128
#define OO 128
#define NG 512   // 4*F gates

typedef short  s16x8 __attribute__((ext_vector_type(8)));
typedef unsigned short u16x8 __attribute__((ext_vector_type(8)));
typedef float  f32x4 __attribute__((ext_vector_type(4)));

static_assert(sizeof(s16x8) == 16, "frag size");

__device__ __forceinline__ unsigned short f2bf(float f) {
    unsigned int u = __builtin_bit_cast(unsigned int, f);
    u += 0x7FFFu + ((u >> 16) & 1u);   // RNE
    return (unsigned short)(u >> 16);
}
__device__ __forceinline__ float bf2f(unsigned short s) {
    unsigned int u = ((unsigned int)s) << 16;
    return __builtin_bit_cast(float, u);
}
__device__ __forceinline__ float sigm(float x) {
    return __builtin_amdgcn_rcpf(1.0f + __expf(-x));
}
__device__ __forceinline__ float tanh_(float x) {
    float e = __expf(2.0f * x);
    return (e - 1.0f) * __builtin_amdgcn_rcpf(e + 1.0f);
}
__device__ __forceinline__ f32x4 splat4(float v) { f32x4 r = {v, v, v, v}; return r; }

// ---------------- prep: cast weights to bf16 (+ transpose Ws/Wn to [o][k]) ----
__global__ void k_prep(const float* __restrict__ Wih, const float* __restrict__ Whh,
                       const float* __restrict__ Ws,  const float* __restrict__ Wn,
                       unsigned short* __restrict__ wihb, unsigned short* __restrict__ whhb,
                       unsigned short* __restrict__ wstb, unsigned short* __restrict__ wntb) {
    int i = blockIdx.x * blockDim.x + threadIdx.x;
    int stride = gridDim.x * blockDim.x;
    for (int idx = i; idx < 4 * NG * FF; idx += stride) {
        wihb[idx] = f2bf(Wih[idx]);
        whhb[idx] = f2bf(Whh[idx]);
    }
    for (int idx = i; idx < 4 * FF * OO; idx += stride) {
        int r = idx >> 14;          // /(128*128)
        int rem = idx & 16383;
        int o = rem >> 7;
        int k = rem & 127;
        // dest [r][o][k] <- src [r][k][o]
        wstb[idx] = f2bf(Ws[(r << 14) + (k << 7) + o]);
        wntb[idx] = f2bf(Wn[(r << 14) + (k << 7) + o]);
    }
}

// ---------------- cast feat to bf16 ------------------------------------------
__global__ void k_castfeat(const float* __restrict__ feat, unsigned short* __restrict__ fbf) {
    int i = blockIdx.x * blockDim.x + threadIdx.x;
    int idx = i * 4;
    if (idx < NN * FF) {
        float4 v = *(const float4*)(feat + idx);
        ushort4 o;
        o.x = f2bf(v.x); o.y = f2bf(v.y); o.z = f2bf(v.z); o.w = f2bf(v.w);
        *(ushort4*)(fbf + idx) = o;
    }
}

// ---------------- segment mean (seg_ids sorted, G=64), float4 vectorized -----
__global__ void k_segmean(const float* __restrict__ feat, const int* __restrict__ seg,
                          float* __restrict__ mean) {
    int g = blockIdx.x;
    int lo, hi;
    { int a = 0, b = NN; while (a < b) { int m = (a + b) >> 1; if (seg[m] < g) a = m + 1; else b = m; } lo = a; }
    { int a = 0, b = NN; while (a < b) { int m = (a + b) >> 1; if (seg[m] < g + 1) a = m + 1; else b = m; } hi = a; }
    int tid = threadIdx.x;
    int d4 = tid & 31;          // float4 slot: dims [d4*4, d4*4+4)
    int part = tid >> 5;        // 8 row-partitions
    float4 s = {0.f, 0.f, 0.f, 0.f};
    for (int row = lo + part; row < hi; row += 8) {
        float4 v = *(const float4*)(feat + (size_t)row * FF + d4 * 4);
        s.x += v.x; s.y += v.y; s.z += v.z; s.w += v.w;
    }
    __shared__ float ps[8][128];
    ps[part][d4 * 4 + 0] = s.x; ps[part][d4 * 4 + 1] = s.y;
    ps[part][d4 * 4 + 2] = s.z; ps[part][d4 * 4 + 3] = s.w;
    __syncthreads();
    if (tid < 128) {
        float tot = 0.f;
#pragma unroll
        for (int p = 0; p < 8; ++p) tot += ps[p][tid];
        mean[g * FF + tid] = tot / fmaxf((float)(hi - lo), 1.0f);
    }
}

// ---------------- deg bucketing, all 4 relations (two-level histogram) -------
// cnt4[r*64 + d] = counts (d=1..16), cnt4[r*64 + 40 + d] = cursor
__global__ void k_count(const int* __restrict__ D0, const int* __restrict__ D1,
                        const int* __restrict__ D2, const int* __restrict__ D3,
                        int* __restrict__ cnt4) {
    int r = blockIdx.y;
    const int* dg = (r == 0) ? D0 : (r == 1) ? D1 : (r == 2) ? D2 : D3;
    __shared__ int lcnt[17];
    if (threadIdx.x < 17) lcnt[threadIdx.x] = 0;
    __syncthreads();
    int n = blockIdx.x * blockDim.x + threadIdx.x;
    if (n < NN) { int d = dg[n]; if (d > 0) atomicAdd(&lcnt[d], 1); }
    __syncthreads();
    if (threadIdx.x >= 1 && threadIdx.x < 17 && lcnt[threadIdx.x])
        atomicAdd(&cnt4[r * 64 + threadIdx.x], lcnt[threadIdx.x]);
}
__global__ void k_offsets(int* __restrict__ cnt4) {
    int r = threadIdx.x;
    if (r < 4 && blockIdx.x == 0) {
        int running = 0;
        for (int d = 16; d >= 1; --d) {             // heavy buckets first
            cnt4[r * 64 + 40 + d] = running;
            running += (cnt4[r * 64 + d] + 15) & ~15;   // pad each bucket to x16
        }
    }
}
__global__ void k_scatter(const int* __restrict__ D0, const int* __restrict__ D1,
                          const int* __restrict__ D2, const int* __restrict__ D3,
                          int* __restrict__ cnt4, int* __restrict__ order4) {
    int r = blockIdx.y;
    const int* dg = (r == 0) ? D0 : (r == 1) ? D1 : (r == 2) ? D2 : D3;
    __shared__ int lcnt[17];
    __shared__ int gbase[17];
    if (threadIdx.x < 17) lcnt[threadIdx.x] = 0;
    __syncthreads();
    int n = blockIdx.x * blockDim.x + threadIdx.x;
    int d = 0, rank = 0;
    if (n < NN) { d = dg[n]; if (d > 0) rank = atomicAdd(&lcnt[d], 1); }
    __syncthreads();
    if (threadIdx.x >= 1 && threadIdx.x < 17 && lcnt[threadIdx.x])
        gbase[threadIdx.x] = atomicAdd(&cnt4[r * 64 + 40 + threadIdx.x], lcnt[threadIdx.x]);
    __syncthreads();
    if (n < NN && d > 0) order4[r * 40960 + gbase[d] + rank] = n;
}

// ---------------- Xih = feat @ Wih[r].T + b, wave-permuted storage ----------
// Wave w owns gate-tiles {w+4j : j=0..7}. Row layout (512 u16 = 1KB):
// u16 index w*128 + col*8 + j  holds gate (w+4j)*16+col.
__global__ __launch_bounds__(256, 4) void k_xih(const unsigned short* __restrict__ fbf,
                                                const unsigned short* __restrict__ wihb,
                                                const float* __restrict__ lb,
                                                unsigned short* __restrict__ xih, int r) {
    int tid = threadIdx.x;
    int w = tid >> 6;
    int l = tid & 63;
    int n0 = blockIdx.x * 16;
    int col = l & 15, grp = l >> 4;

    f32x4 acc[8];
#pragma unroll
    for (int j = 0; j < 8; ++j) acc[j] = splat4(lb[r * NG + (w + 4 * j) * 16 + col]);

    s16x8 a[4];
    const unsigned short* ap = fbf + (size_t)(n0 + col) * FF + grp * 8;
#pragma unroll
    for (int kt = 0; kt < 4; ++kt) a[kt] = *(const s16x8*)(ap + kt * 32);

    const unsigned short* wb = wihb + (size_t)r * NG * FF + col * FF + grp * 8;
#pragma unroll
    for (int j = 0; j < 8; ++j) {
#pragma unroll
        for (int kt = 0; kt < 4; ++kt) {
            s16x8 b = *(const s16x8*)(wb + (size_t)(w + 4 * j) * 16 * FF + kt * 32);
            acc[j] = __builtin_amdgcn_mfma_f32_16x16x32_bf16(a[kt], b, acc[j], 0, 0, 0);
        }
    }
#pragma unroll
    for (int q = 0; q < 4; ++q) {
        u16x8 hv;
#pragma unroll
        for (int j = 0; j < 8; ++j) hv[j] = f2bf(acc[j][q]);
        *(u16x8*)(xih + (size_t)(n0 + grp * 4 + q) * NG + w * 128 + col * 8) = hv;
    }
}

// ---------------- bucketed LSTM, Whh in registers, persistent over 2 groups --
// 256 thr = 4 waves; Whh slice = 32 s16x8 (AGPR-resident, ~250 regs total ->
// 2 waves/SIMD cap). Per step: 4 prefetched gathers + 4 LDS h-reads + 32 MFMA
// + shared-rcp activations (8 trans/elem) + cvt_pk bf16 store; ONE barrier/step.
#define LSTM_BLOCKS 1280
#define LSTM_GROUPS 2
__global__ __launch_bounds__(256, 2) void k_lstm(const unsigned short* __restrict__ xih,
                                                 const unsigned short* __restrict__ whhb,
                                                 const int* __restrict__ order,
                                                 const int* __restrict__ nbr,
                                                 const int* __restrict__ deg,
                                                 unsigned short* __restrict__ hfin, int r) {
    __shared__ int nodes[16];
    __shared__ int nbrs[16][16];   // premultiplied byte offsets (node * 1024)
    __shared__ unsigned short hbuf[2][2048];   // 2 x (16 rows x 128 dims bf16), XOR-swizzled
    int tid = threadIdx.x;
    int w = tid >> 6, l = tid & 63;
    int col = l & 15, grp = l >> 4;

    // hoist this wave's entire Whh slice into registers (invariant across groups)
    const unsigned short* whhp = whhb + (size_t)r * NG * FF + col * FF + grp * 8;
    s16x8 breg[8][4];
#pragma unroll
    for (int j = 0; j < 8; ++j)
#pragma unroll
        for (int kt = 0; kt < 4; ++kt)
            breg[j][kt] = *(const s16x8*)(whhp + (size_t)(w + 4 * j) * 16 * FF + kt * 32);

    const char* xbc = (const char*)(xih + w * 128 + col * 8);

    // hoisted LDS swizzle addresses (invariant)
    int rbyte[4];
#pragma unroll
    for (int kt = 0; kt < 4; ++kt)
        rbyte[kt] = (col * 256 + kt * 64 + grp * 16) ^ ((col & 7) << 4);
    int wbyte0[4], wbyte1[4];
#pragma unroll
    for (int q = 0; q < 4; ++q) {
        int node = grp * 4 + q;
        wbyte0[q] = (node * 256 + (w * 16 + col) * 2) ^ ((node & 7) << 4);
        wbyte1[q] = (node * 256 + ((w + 4) * 16 + col) * 2) ^ ((node & 7) << 4);
    }

    for (int gi = 0; gi < LSTM_GROUPS; ++gi) {
        int g0 = (blockIdx.x + gi * LSTM_BLOCKS) * 16;
        __syncthreads();   // prior group's reads of nodes/nbrs/hbuf complete
        if (tid < 16) nodes[tid] = order[g0 + tid];
        __syncthreads();
        if (nodes[0] < 0) continue;          // uniform across block
        int degv = deg[nodes[0]];

        {
            int row = tid >> 4, t = tid & 15;
            int nd = nodes[row]; if (nd < 0) nd = 0;
            nbrs[row][t] = nbr[nd * DDEG + t] << 10;   // byte offset into xih
        }
        __syncthreads();

        float cst[8];
#pragma unroll
        for (int e = 0; e < 8; ++e) cst[e] = 0.f;

        // prefetch gathers for t=0
        u16x8 cur[4], nxt[4];
#pragma unroll
        for (int q = 0; q < 4; ++q) {
            cur[q] = *(const u16x8*)(xbc + (unsigned)nbrs[grp * 4 + q][0]);
            nxt[q] = cur[q];
        }

        for (int t = 0; t < degv; ++t) {
            // issue next-step gathers early (overlap with MFMA + activations)
            if (t + 1 < degv) {
#pragma unroll
                for (int q = 0; q < 4; ++q)
                    nxt[q] = *(const u16x8*)(xbc + (unsigned)nbrs[grp * 4 + q][t + 1]);
            }
            f32x4 acc[8];
#pragma unroll
            for (int j = 0; j < 8; ++j)
#pragma unroll
                for (int q = 0; q < 4; ++q)
                    acc[j][q] = bf2f(cur[q][j]);

            if (t > 0) {
                const char* hrd = (const char*)hbuf[t & 1];
                s16x8 ah[4];
#pragma unroll
                for (int kt = 0; kt < 4; ++kt) ah[kt] = *(const s16x8*)(hrd + rbyte[kt]);
#pragma unroll
                for (int j = 0; j < 8; ++j)
#pragma unroll
                    for (int kt = 0; kt < 4; ++kt)
                        acc[j] = __builtin_amdgcn_mfma_f32_16x16x32_bf16(ah[kt], breg[j][kt], acc[j], 0, 0, 0);
            }
            // shared-rcp activations (8 trans/elem instead of 10):
            // i*g = (C-1)/((1+A)(C+1)), f*c = c/(1+B), o*tanh(cn) = (E-1)/((1+D)(E+1))
            char* hwr = (char*)hbuf[(t + 1) & 1];
#pragma unroll
            for (int q = 0; q < 4; ++q) {
                float hv01[2];
#pragma unroll
                for (int ji = 0; ji < 2; ++ji) {
                    float A = __expf(-acc[ji][q]);
                    float B = __expf(-acc[ji + 2][q]);
                    float C = __expf(2.0f * acc[ji + 4][q]);
                    float D = __expf(-acc[ji + 6][q]);
                    float ig = (C - 1.0f) * __builtin_amdgcn_rcpf((1.0f + A) * (C + 1.0f));
                    float fc = cst[ji * 4 + q] * __builtin_amdgcn_rcpf(1.0f + B);
                    float cv = fc + ig;
                    cst[ji * 4 + q] = cv;
                    float E = __expf(2.0f * cv);
                    hv01[ji] = (E - 1.0f) * __builtin_amdgcn_rcpf((1.0f + D) * (E + 1.0f));
                }
                unsigned pk;
                asm("v_cvt_pk_bf16_f32 %0, %1, %2" : "=v"(pk) : "v"(hv01[0]), "v"(hv01[1]));
                *(unsigned short*)(hwr + wbyte0[q]) = (unsigned short)pk;
                *(unsigned short*)(hwr + wbyte1[q]) = (unsigned short)(pk >> 16);
            }
#pragma unroll
            for (int q = 0; q < 4; ++q) cur[q] = nxt[q];
            __syncthreads();
        }
        // write h_fin from hbuf[degv & 1]
        const char* hf = (const char*)hbuf[degv & 1];
        int row = tid >> 4;
        int nd = nodes[row];
        if (nd >= 0) {
            int off = (tid & 15) * 16;                    // byte within row
            int byte = (row * 256 + off) ^ ((row & 7) << 4);
            u16x8 v = *(const u16x8*)(hf + byte);
            *(u16x8*)(hfin + (size_t)nd * FF + off / 2) = v;
        }
    }
}

// ---------------- fused projection: all 4 r + max/add + residual -------------
// deg-masked h-frags (deg==0 -> zero contribution) so hfin needs no memset.
__global__ __launch_bounds__(256, 2) void k_proj(const unsigned short* __restrict__ fbf,
                                                 const unsigned short* __restrict__ hfin4,
                                                 const unsigned short* __restrict__ wstb,
                                                 const unsigned short* __restrict__ wntb,
                                                 const float* __restrict__ bo,
                                                 const float* __restrict__ mean,
                                                 const int* __restrict__ seg,
                                                 const int* __restrict__ D0, const int* __restrict__ D1,
                                                 const int* __restrict__ D2, const int* __restrict__ D3,
                                                 float* __restrict__ out) {
    int wv = threadIdx.x >> 6, l = threadIdx.x & 63;
    int n0 = blockIdx.x * 64 + wv * 16;
    int col = l & 15, grp = l >> 4;

    s16x8 af[4];
    const unsigned short* fp = fbf + (size_t)(n0 + col) * FF + grp * 8;
#pragma unroll
    for (int kt = 0; kt < 4; ++kt) af[kt] = *(const s16x8*)(fp + kt * 32);

    const s16x8 zfrag = {0, 0, 0, 0, 0, 0, 0, 0};

    f32x4 m01[8], m23[8];
#pragma unroll
    for (int r = 0; r < 4; ++r) {
        const int* dg = (r == 0) ? D0 : (r == 1) ? D1 : (r == 2) ? D2 : D3;
        int dval = dg[n0 + col];
        f32x4 acc[8];
#pragma unroll
        for (int t = 0; t < 8; ++t) acc[t] = splat4(bo[r * OO + t * 16 + col]);

        const unsigned short* wsb = wstb + (size_t)r * OO * FF + col * FF + grp * 8;
        const unsigned short* wnb = wntb + (size_t)r * OO * FF + col * FF + grp * 8;
        const unsigned short* hp = hfin4 + (size_t)r * NN * FF + (size_t)(n0 + col) * FF + grp * 8;
#pragma unroll
        for (int kt = 0; kt < 4; ++kt) {
            s16x8 ah = *(const s16x8*)(hp + kt * 32);
            ah = (dval > 0) ? ah : zfrag;
#pragma unroll
            for (int t = 0; t < 8; ++t) {
                s16x8 b1 = *(const s16x8*)(wsb + t * 16 * FF + kt * 32);
                acc[t] = __builtin_amdgcn_mfma_f32_16x16x32_bf16(af[kt], b1, acc[t], 0, 0, 0);
                s16x8 b2 = *(const s16x8*)(wnb + t * 16 * FF + kt * 32);
                acc[t] = __builtin_amdgcn_mfma_f32_16x16x32_bf16(ah, b2, acc[t], 0, 0, 0);
            }
        }
#pragma unroll
        for (int t = 0; t < 8; ++t) {
            if (r == 0)      m01[t] = acc[t];
            else if (r == 1) { m01[t][0] = fmaxf(m01[t][0], acc[t][0]); m01[t][1] = fmaxf(m01[t][1], acc[t][1]);
                               m01[t][2] = fmaxf(m01[t][2], acc[t][2]); m01[t][3] = fmaxf(m01[t][3], acc[t][3]); }
            else if (r == 2) m23[t] = acc[t];
            else             { m23[t][0] = fmaxf(m23[t][0], acc[t][0]); m23[t][1] = fmaxf(m23[t][1], acc[t][1]);
                               m23[t][2] = fmaxf(m23[t][2], acc[t][2]); m23[t][3] = fmaxf(m23[t][3], acc[t][3]); }
        }
    }
#pragma unroll
    for (int q = 0; q < 4; ++q) {
        int node = n0 + grp * 4 + q;
        int sg = seg[node];
#pragma unroll
        for (int t = 0; t < 8; ++t) {
            int idx = node * OO + t * 16 + col;
            out[idx] = mean[sg * FF + t * 16 + col] + m01[t][q] + m23[t][q];
        }
    }
}

extern "C" void kernel_launch(void* const* d_in, const int* in_sizes, int n_in,
                              void* d_out, int out_size, void* d_ws, size_t ws_size,
                              hipStream_t stream) {
    const float* feat = (const float*)d_in[0];
    const int* nbr[4] = {(const int*)d_in[1], (const int*)d_in[3], (const int*)d_in[5], (const int*)d_in[7]};
    const int* dgp[4] = {(const int*)d_in[2], (const int*)d_in[4], (const int*)d_in[6], (const int*)d_in[8]};
    const int* seg   = (const int*)d_in[9];
    const float* Wih = (const float*)d_in[10];
    const float* Whh = (const float*)d_in[11];
    const float* lb  = (const float*)d_in[12];
    const float* Ws  = (const float*)d_in[13];
    const float* Wn  = (const float*)d_in[14];
    const float* bo  = (const float*)d_in[15];

    char* ws = (char*)d_ws;
    float*          mean  = (float*)(ws + 0);                      //     32,768
    unsigned short* fbf   = (unsigned short*)(ws + 32768);         // 10,240,000
    unsigned short* wihb  = (unsigned short*)(ws + 10272768);      //    524,288
    unsigned short* whhb  = (unsigned short*)(ws + 10797056);      //    524,288
    unsigned short* wstb  = (unsigned short*)(ws + 11321344);      //    131,072
    unsigned short* wntb  = (unsigned short*)(ws + 11452416);      //    131,072
    unsigned short* xih   = (unsigned short*)(ws + 11583488);      // 40,960,000
    unsigned short* hfin4 = (unsigned short*)(ws + 52543488);      // 40,960,000 (4 slices)
    int*            order4= (int*)(ws + 93503488);                 //    655,360
    int*            cnt4  = (int*)(ws + 94158848);                 //      1,024

    hipMemsetAsync(order4, 0xFF, 655360, stream);
    hipMemsetAsync(cnt4, 0, 1024, stream);

    k_prep<<<256, 256, 0, stream>>>(Wih, Whh, Ws, Wn, wihb, whhb, wstb, wntb);
    k_castfeat<<<5000, 256, 0, stream>>>(feat, fbf);
    k_segmean<<<64, 256, 0, stream>>>(feat, seg, mean);
    k_count<<<dim3(157, 4), 256, 0, stream>>>(dgp[0], dgp[1], dgp[2], dgp[3], cnt4);
    k_offsets<<<1, 64, 0, stream>>>(cnt4);
    k_scatter<<<dim3(157, 4), 256, 0, stream>>>(dgp[0], dgp[1], dgp[2], dgp[3], cnt4, order4);

    for (int r = 0; r < 4; ++r) {
        k_xih<<<2500, 256, 0, stream>>>(fbf, wihb, lb, xih, r);
        k_lstm<<<LSTM_BLOCKS, 256, 0, stream>>>(xih, whhb, order4 + r * 40960, nbr[r], dgp[r],
                                                hfin4 + (size_t)r * NN * FF, r);
    }
    k_proj<<<625, 256, 0, stream>>>(fbf, hfin4, wstb, wntb, bo, mean, seg,
                                    dgp[0], dgp[1], dgp[2], dgp[3], (float*)d_out);
}

// Round 8
// 612.570 us; speedup vs baseline: 3.6235x; 1.0585x over previous
//
#include <hip/hip_runtime.h>

#define NN 40000
#define DDEG 16
#define FF 128
#define OO 128
#define NG 512   // 4*F gates
#define XIH_ELEMS 20480000   // NN*NG u16 per relation

typedef short  s16x8 __attribute__((ext_vector_type(8)));
typedef unsigned short u16x8 __attribute__((ext_vector_type(8)));
typedef float  f32x4 __attribute__((ext_vector_type(4)));

static_assert(sizeof(s16x8) == 16, "frag size");

__device__ __forceinline__ unsigned short f2bf(float f) {
    unsigned int u = __builtin_bit_cast(unsigned int, f);
    u += 0x7FFFu + ((u >> 16) & 1u);   // RNE
    return (unsigned short)(u >> 16);
}
__device__ __forceinline__ float bf2f(unsigned short s) {
    unsigned int u = ((unsigned int)s) << 16;
    return __builtin_bit_cast(float, u);
}
__device__ __forceinline__ f32x4 splat4(float v) { f32x4 r = {v, v, v, v}; return r; }

// ---------------- prep: cast weights to bf16 (+ transpose Ws/Wn to [o][k]) ----
__global__ void k_prep(const float* __restrict__ Wih, const float* __restrict__ Whh,
                       const float* __restrict__ Ws,  const float* __restrict__ Wn,
                       unsigned short* __restrict__ wihb, unsigned short* __restrict__ whhb,
                       unsigned short* __restrict__ wstb, unsigned short* __restrict__ wntb) {
    int i = blockIdx.x * blockDim.x + threadIdx.x;
    int stride = gridDim.x * blockDim.x;
    for (int idx = i; idx < 4 * NG * FF; idx += stride) {
        wihb[idx] = f2bf(Wih[idx]);
        whhb[idx] = f2bf(Whh[idx]);
    }
    for (int idx = i; idx < 4 * FF * OO; idx += stride) {
        int r = idx >> 14;          // /(128*128)
        int rem = idx & 16383;
        int o = rem >> 7;
        int k = rem & 127;
        // dest [r][o][k] <- src [r][k][o]
        wstb[idx] = f2bf(Ws[(r << 14) + (k << 7) + o]);
        wntb[idx] = f2bf(Wn[(r << 14) + (k << 7) + o]);
    }
}

// ---------------- cast feat to bf16 ------------------------------------------
__global__ void k_castfeat(const float* __restrict__ feat, unsigned short* __restrict__ fbf) {
    int i = blockIdx.x * blockDim.x + threadIdx.x;
    int idx = i * 4;
    if (idx < NN * FF) {
        float4 v = *(const float4*)(feat + idx);
        ushort4 o;
        o.x = f2bf(v.x); o.y = f2bf(v.y); o.z = f2bf(v.z); o.w = f2bf(v.w);
        *(ushort4*)(fbf + idx) = o;
    }
}

// ---------------- segment mean (seg_ids sorted, G=64), float4 vectorized -----
__global__ void k_segmean(const float* __restrict__ feat, const int* __restrict__ seg,
                          float* __restrict__ mean) {
    int g = blockIdx.x;
    int lo, hi;
    { int a = 0, b = NN; while (a < b) { int m = (a + b) >> 1; if (seg[m] < g) a = m + 1; else b = m; } lo = a; }
    { int a = 0, b = NN; while (a < b) { int m = (a + b) >> 1; if (seg[m] < g + 1) a = m + 1; else b = m; } hi = a; }
    int tid = threadIdx.x;
    int d4 = tid & 31;          // float4 slot: dims [d4*4, d4*4+4)
    int part = tid >> 5;        // 8 row-partitions
    float4 s = {0.f, 0.f, 0.f, 0.f};
    for (int row = lo + part; row < hi; row += 8) {
        float4 v = *(const float4*)(feat + (size_t)row * FF + d4 * 4);
        s.x += v.x; s.y += v.y; s.z += v.z; s.w += v.w;
    }
    __shared__ float ps[8][128];
    ps[part][d4 * 4 + 0] = s.x; ps[part][d4 * 4 + 1] = s.y;
    ps[part][d4 * 4 + 2] = s.z; ps[part][d4 * 4 + 3] = s.w;
    __syncthreads();
    if (tid < 128) {
        float tot = 0.f;
#pragma unroll
        for (int p = 0; p < 8; ++p) tot += ps[p][tid];
        mean[g * FF + tid] = tot / fmaxf((float)(hi - lo), 1.0f);
    }
}

// ---------------- deg bucketing, all 4 relations (two-level histogram) -------
__global__ void k_count(const int* __restrict__ D0, const int* __restrict__ D1,
                        const int* __restrict__ D2, const int* __restrict__ D3,
                        int* __restrict__ cnt4) {
    int r = blockIdx.y;
    const int* dg = (r == 0) ? D0 : (r == 1) ? D1 : (r == 2) ? D2 : D3;
    __shared__ int lcnt[17];
    if (threadIdx.x < 17) lcnt[threadIdx.x] = 0;
    __syncthreads();
    int n = blockIdx.x * blockDim.x + threadIdx.x;
    if (n < NN) { int d = dg[n]; if (d > 0) atomicAdd(&lcnt[d], 1); }
    __syncthreads();
    if (threadIdx.x >= 1 && threadIdx.x < 17 && lcnt[threadIdx.x])
        atomicAdd(&cnt4[r * 64 + threadIdx.x], lcnt[threadIdx.x]);
}
__global__ void k_offsets(int* __restrict__ cnt4) {
    int r = threadIdx.x;
    if (r < 4 && blockIdx.x == 0) {
        int running = 0;
        for (int d = 16; d >= 1; --d) {             // heavy buckets first
            cnt4[r * 64 + 40 + d] = running;
            running += (cnt4[r * 64 + d] + 15) & ~15;   // pad each bucket to x16
        }
    }
}
__global__ void k_scatter(const int* __restrict__ D0, const int* __restrict__ D1,
                          const int* __restrict__ D2, const int* __restrict__ D3,
                          int* __restrict__ cnt4, int* __restrict__ order4) {
    int r = blockIdx.y;
    const int* dg = (r == 0) ? D0 : (r == 1) ? D1 : (r == 2) ? D2 : D3;
    __shared__ int lcnt[17];
    __shared__ int gbase[17];
    if (threadIdx.x < 17) lcnt[threadIdx.x] = 0;
    __syncthreads();
    int n = blockIdx.x * blockDim.x + threadIdx.x;
    int d = 0, rank = 0;
    if (n < NN) { d = dg[n]; if (d > 0) rank = atomicAdd(&lcnt[d], 1); }
    __syncthreads();
    if (threadIdx.x >= 1 && threadIdx.x < 17 && lcnt[threadIdx.x])
        gbase[threadIdx.x] = atomicAdd(&cnt4[r * 64 + 40 + threadIdx.x], lcnt[threadIdx.x]);
    __syncthreads();
    if (n < NN && d > 0) order4[r * 40960 + gbase[d] + rank] = n;
}

// ---------------- Xih = feat @ Wih[r].T + b, wave-permuted storage ----------
// r = rbase + blockIdx.y; output buffer strided by XIH_ELEMS per y-slice.
__global__ __launch_bounds__(256, 4) void k_xih(const unsigned short* __restrict__ fbf,
                                                const unsigned short* __restrict__ wihb,
                                                const float* __restrict__ lb,
                                                unsigned short* __restrict__ xih, int rbase) {
    int r = rbase + blockIdx.y;
    unsigned short* xr = xih + (size_t)blockIdx.y * XIH_ELEMS;
    int tid = threadIdx.x;
    int w = tid >> 6;
    int l = tid & 63;
    int n0 = blockIdx.x * 16;
    int col = l & 15, grp = l >> 4;

    f32x4 acc[8];
#pragma unroll
    for (int j = 0; j < 8; ++j) acc[j] = splat4(lb[r * NG + (w + 4 * j) * 16 + col]);

    s16x8 a[4];
    const unsigned short* ap = fbf + (size_t)(n0 + col) * FF + grp * 8;
#pragma unroll
    for (int kt = 0; kt < 4; ++kt) a[kt] = *(const s16x8*)(ap + kt * 32);

    const unsigned short* wb = wihb + (size_t)r * NG * FF + col * FF + grp * 8;
#pragma unroll
    for (int j = 0; j < 8; ++j) {
#pragma unroll
        for (int kt = 0; kt < 4; ++kt) {
            s16x8 b = *(const s16x8*)(wb + (size_t)(w + 4 * j) * 16 * FF + kt * 32);
            acc[j] = __builtin_amdgcn_mfma_f32_16x16x32_bf16(a[kt], b, acc[j], 0, 0, 0);
        }
    }
#pragma unroll
    for (int q = 0; q < 4; ++q) {
        u16x8 hv;
#pragma unroll
        for (int j = 0; j < 8; ++j) hv[j] = f2bf(acc[j][q]);
        *(u16x8*)(xr + (size_t)(n0 + grp * 4 + q) * NG + w * 128 + col * 8) = hv;
    }
}

// ---------------- bucketed LSTM, Whh in registers, persistent over 2 groups --
// r = rbase + blockIdx.y (merged dispatch when ws allows). 256 thr = 4 waves;
// Whh slice = 32 s16x8 in regs. Per step: 4 prefetched gathers + 4 LDS h-reads
// + 32 MFMA + shared-rcp activations; double-buffered swizzled LDS; 1 barrier/step.
#define LSTM_BLOCKS 1280
#define LSTM_GROUPS 2
__global__ __launch_bounds__(256, 2) void k_lstm(const unsigned short* __restrict__ xih,
                                                 const unsigned short* __restrict__ whhb,
                                                 const int* __restrict__ order4,
                                                 const int* __restrict__ N0, const int* __restrict__ N1,
                                                 const int* __restrict__ N2, const int* __restrict__ N3,
                                                 const int* __restrict__ D0, const int* __restrict__ D1,
                                                 const int* __restrict__ D2, const int* __restrict__ D3,
                                                 unsigned short* __restrict__ hfin4, int rbase) {
    int r = rbase + blockIdx.y;
    const unsigned short* xr = xih + (size_t)blockIdx.y * XIH_ELEMS;
    const int* nbr = (r == 0) ? N0 : (r == 1) ? N1 : (r == 2) ? N2 : N3;
    const int* deg = (r == 0) ? D0 : (r == 1) ? D1 : (r == 2) ? D2 : D3;
    const int* order = order4 + r * 40960;
    unsigned short* hfin = hfin4 + (size_t)r * NN * FF;

    __shared__ int nodes[16];
    __shared__ int nbrs[16][16];   // premultiplied byte offsets (node * 1024)
    __shared__ unsigned short hbuf[2][2048];   // 2 x (16 rows x 128 dims bf16), XOR-swizzled
    int tid = threadIdx.x;
    int w = tid >> 6, l = tid & 63;
    int col = l & 15, grp = l >> 4;

    // hoist this wave's entire Whh slice into registers (invariant across groups)
    const unsigned short* whhp = whhb + (size_t)r * NG * FF + col * FF + grp * 8;
    s16x8 breg[8][4];
#pragma unroll
    for (int j = 0; j < 8; ++j)
#pragma unroll
        for (int kt = 0; kt < 4; ++kt)
            breg[j][kt] = *(const s16x8*)(whhp + (size_t)(w + 4 * j) * 16 * FF + kt * 32);

    const char* xbc = (const char*)(xr + w * 128 + col * 8);

    // hoisted LDS swizzle addresses (invariant)
    int rbyte[4];
#pragma unroll
    for (int kt = 0; kt < 4; ++kt)
        rbyte[kt] = (col * 256 + kt * 64 + grp * 16) ^ ((col & 7) << 4);
    int wbyte0[4], wbyte1[4];
#pragma unroll
    for (int q = 0; q < 4; ++q) {
        int node = grp * 4 + q;
        wbyte0[q] = (node * 256 + (w * 16 + col) * 2) ^ ((node & 7) << 4);
        wbyte1[q] = (node * 256 + ((w + 4) * 16 + col) * 2) ^ ((node & 7) << 4);
    }

    for (int gi = 0; gi < LSTM_GROUPS; ++gi) {
        int g0 = (blockIdx.x + gi * LSTM_BLOCKS) * 16;
        __syncthreads();   // prior group's reads of nodes/nbrs/hbuf complete
        if (tid < 16) nodes[tid] = order[g0 + tid];
        __syncthreads();
        if (nodes[0] < 0) continue;          // uniform across block
        int degv = deg[nodes[0]];

        {
            int row = tid >> 4, t = tid & 15;
            int nd = nodes[row]; if (nd < 0) nd = 0;
            nbrs[row][t] = nbr[nd * DDEG + t] << 10;   // byte offset into xih slice
        }
        __syncthreads();

        float cst[8];
#pragma unroll
        for (int e = 0; e < 8; ++e) cst[e] = 0.f;

        // prefetch gathers for t=0
        u16x8 cur[4], nxt[4];
#pragma unroll
        for (int q = 0; q < 4; ++q) {
            cur[q] = *(const u16x8*)(xbc + (unsigned)nbrs[grp * 4 + q][0]);
            nxt[q] = cur[q];
        }

        for (int t = 0; t < degv; ++t) {
            // issue next-step gathers early (overlap with MFMA + activations)
            if (t + 1 < degv) {
#pragma unroll
                for (int q = 0; q < 4; ++q)
                    nxt[q] = *(const u16x8*)(xbc + (unsigned)nbrs[grp * 4 + q][t + 1]);
            }
            f32x4 acc[8];
#pragma unroll
            for (int j = 0; j < 8; ++j)
#pragma unroll
                for (int q = 0; q < 4; ++q)
                    acc[j][q] = bf2f(cur[q][j]);

            if (t > 0) {
                const char* hrd = (const char*)hbuf[t & 1];
                s16x8 ah[4];
#pragma unroll
                for (int kt = 0; kt < 4; ++kt) ah[kt] = *(const s16x8*)(hrd + rbyte[kt]);
#pragma unroll
                for (int j = 0; j < 8; ++j)
#pragma unroll
                    for (int kt = 0; kt < 4; ++kt)
                        acc[j] = __builtin_amdgcn_mfma_f32_16x16x32_bf16(ah[kt], breg[j][kt], acc[j], 0, 0, 0);
            }
            // shared-rcp activations (8 trans/elem):
            // i*g = (C-1)/((1+A)(C+1)), f*c = c/(1+B), o*tanh(cn) = (E-1)/((1+D)(E+1))
            char* hwr = (char*)hbuf[(t + 1) & 1];
#pragma unroll
            for (int q = 0; q < 4; ++q) {
#pragma unroll
                for (int ji = 0; ji < 2; ++ji) {
                    float A = __expf(-acc[ji][q]);
                    float B = __expf(-acc[ji + 2][q]);
                    float C = __expf(2.0f * acc[ji + 4][q]);
                    float D = __expf(-acc[ji + 6][q]);
                    float ig = (C - 1.0f) * __builtin_amdgcn_rcpf((1.0f + A) * (C + 1.0f));
                    float fc = cst[ji * 4 + q] * __builtin_amdgcn_rcpf(1.0f + B);
                    float cv = fc + ig;
                    cst[ji * 4 + q] = cv;
                    float E = __expf(2.0f * cv);
                    float hv = (E - 1.0f) * __builtin_amdgcn_rcpf((1.0f + D) * (E + 1.0f));
                    *(unsigned short*)(hwr + (ji == 0 ? wbyte0[q] : wbyte1[q])) = f2bf(hv);
                }
            }
#pragma unroll
            for (int q = 0; q < 4; ++q) cur[q] = nxt[q];
            __syncthreads();
        }
        // write h_fin from hbuf[degv & 1]
        const char* hf = (const char*)hbuf[degv & 1];
        int row = tid >> 4;
        int nd = nodes[row];
        if (nd >= 0) {
            int off = (tid & 15) * 16;                    // byte within row
            int byte = (row * 256 + off) ^ ((row & 7) << 4);
            u16x8 v = *(const u16x8*)(hf + byte);
            *(u16x8*)(hfin + (size_t)nd * FF + off / 2) = v;
        }
    }
}

// ---------------- projection half: max of two relations -> bf16 partial ------
// blockIdx.y = pair p: h_p = max(conv(2p), conv(2p+1)); deg-masked h-frags.
__global__ __launch_bounds__(256, 3) void k_projh(const unsigned short* __restrict__ fbf,
                                                  const unsigned short* __restrict__ hfin4,
                                                  const unsigned short* __restrict__ wstb,
                                                  const unsigned short* __restrict__ wntb,
                                                  const float* __restrict__ bo,
                                                  const int* __restrict__ D0, const int* __restrict__ D1,
                                                  const int* __restrict__ D2, const int* __restrict__ D3,
                                                  unsigned short* __restrict__ tmp) {
    int p = blockIdx.y;
    int wv = threadIdx.x >> 6, l = threadIdx.x & 63;
    int n0 = blockIdx.x * 64 + wv * 16;
    int col = l & 15, grp = l >> 4;

    s16x8 af[4];
    const unsigned short* fp = fbf + (size_t)(n0 + col) * FF + grp * 8;
#pragma unroll
    for (int kt = 0; kt < 4; ++kt) af[kt] = *(const s16x8*)(fp + kt * 32);

    const s16x8 zfrag = {0, 0, 0, 0, 0, 0, 0, 0};

    f32x4 m[8];
#pragma unroll
    for (int rr = 0; rr < 2; ++rr) {
        int r = p * 2 + rr;
        const int* dg = (r == 0) ? D0 : (r == 1) ? D1 : (r == 2) ? D2 : D3;
        int dval = dg[n0 + col];
        f32x4 acc[8];
#pragma unroll
        for (int t = 0; t < 8; ++t) acc[t] = splat4(bo[r * OO + t * 16 + col]);

        const unsigned short* wsb = wstb + (size_t)r * OO * FF + col * FF + grp * 8;
        const unsigned short* wnb = wntb + (size_t)r * OO * FF + col * FF + grp * 8;
        const unsigned short* hp = hfin4 + (size_t)r * NN * FF + (size_t)(n0 + col) * FF + grp * 8;
#pragma unroll
        for (int kt = 0; kt < 4; ++kt) {
            s16x8 ah = *(const s16x8*)(hp + kt * 32);
            ah = (dval > 0) ? ah : zfrag;
#pragma unroll
            for (int t = 0; t < 8; ++t) {
                s16x8 b1 = *(const s16x8*)(wsb + t * 16 * FF + kt * 32);
                acc[t] = __builtin_amdgcn_mfma_f32_16x16x32_bf16(af[kt], b1, acc[t], 0, 0, 0);
                s16x8 b2 = *(const s16x8*)(wnb + t * 16 * FF + kt * 32);
                acc[t] = __builtin_amdgcn_mfma_f32_16x16x32_bf16(ah, b2, acc[t], 0, 0, 0);
            }
        }
#pragma unroll
        for (int t = 0; t < 8; ++t) {
            if (rr == 0) m[t] = acc[t];
            else { m[t][0] = fmaxf(m[t][0], acc[t][0]); m[t][1] = fmaxf(m[t][1], acc[t][1]);
                   m[t][2] = fmaxf(m[t][2], acc[t][2]); m[t][3] = fmaxf(m[t][3], acc[t][3]); }
        }
    }
    unsigned short* tp = tmp + (size_t)p * NN * OO;
#pragma unroll
    for (int q = 0; q < 4; ++q) {
        int node = n0 + grp * 4 + q;
#pragma unroll
        for (int t = 0; t < 8; ++t)
            tp[node * OO + t * 16 + col] = f2bf(m[t][q]);
    }
}

// ---------------- combine: out = mean[seg] + h01 + h23 -----------------------
__global__ void k_combine(const unsigned short* __restrict__ tmp,
                          const float* __restrict__ mean, const int* __restrict__ seg,
                          float* __restrict__ out) {
    int i = blockIdx.x * blockDim.x + threadIdx.x;
    int idx4 = i * 4;
    if (idx4 >= NN * OO) return;
    int node = idx4 >> 7;
    int dim = idx4 & 127;
    ushort4 a = *(const ushort4*)(tmp + idx4);
    ushort4 b = *(const ushort4*)(tmp + (size_t)NN * OO + idx4);
    float4 mv = *(const float4*)(mean + seg[node] * FF + dim);
    float4 o;
    o.x = mv.x + bf2f(a.x) + bf2f(b.x);
    o.y = mv.y + bf2f(a.y) + bf2f(b.y);
    o.z = mv.z + bf2f(a.z) + bf2f(b.z);
    o.w = mv.w + bf2f(a.w) + bf2f(b.w);
    *(float4*)(out + idx4) = o;
}

extern "C" void kernel_launch(void* const* d_in, const int* in_sizes, int n_in,
                              void* d_out, int out_size, void* d_ws, size_t ws_size,
                              hipStream_t stream) {
    const float* feat = (const float*)d_in[0];
    const int* nbr[4] = {(const int*)d_in[1], (const int*)d_in[3], (const int*)d_in[5], (const int*)d_in[7]};
    const int* dgp[4] = {(const int*)d_in[2], (const int*)d_in[4], (const int*)d_in[6], (const int*)d_in[8]};
    const int* seg   = (const int*)d_in[9];
    const float* Wih = (const float*)d_in[10];
    const float* Whh = (const float*)d_in[11];
    const float* lb  = (const float*)d_in[12];
    const float* Ws  = (const float*)d_in[13];
    const float* Wn  = (const float*)d_in[14];
    const float* bo  = (const float*)d_in[15];

    char* ws = (char*)d_ws;
    float*          mean  = (float*)(ws + 0);                      //     32,768
    unsigned short* fbf   = (unsigned short*)(ws + 32768);         // 10,240,000
    unsigned short* wihb  = (unsigned short*)(ws + 10272768);      //    524,288
    unsigned short* whhb  = (unsigned short*)(ws + 10797056);      //    524,288
    unsigned short* wstb  = (unsigned short*)(ws + 11321344);      //    131,072
    unsigned short* wntb  = (unsigned short*)(ws + 11452416);      //    131,072
    unsigned short* xih   = (unsigned short*)(ws + 11583488);      // 4x or 1x 40,960,000

    const int big = (ws_size >= 217039872ULL);
    size_t xih_bytes = big ? 163840000ULL : 40960000ULL;
    unsigned short* hfin4 = (unsigned short*)(ws + 11583488 + xih_bytes);          // 40,960,000
    int*            order4= (int*)(ws + 11583488 + xih_bytes + 40960000);          //    655,360
    int*            cnt4  = (int*)(ws + 11583488 + xih_bytes + 40960000 + 655360); //      1,024
    unsigned short* tmp   = xih;   // xih dead after lstm; 20,480,000 B for 2 bf16 partials

    hipMemsetAsync(order4, 0xFF, 655360, stream);
    hipMemsetAsync(cnt4, 0, 1024, stream);

    k_prep<<<256, 256, 0, stream>>>(Wih, Whh, Ws, Wn, wihb, whhb, wstb, wntb);
    k_castfeat<<<5000, 256, 0, stream>>>(feat, fbf);
    k_segmean<<<64, 256, 0, stream>>>(feat, seg, mean);
    k_count<<<dim3(157, 4), 256, 0, stream>>>(dgp[0], dgp[1], dgp[2], dgp[3], cnt4);
    k_offsets<<<1, 64, 0, stream>>>(cnt4);
    k_scatter<<<dim3(157, 4), 256, 0, stream>>>(dgp[0], dgp[1], dgp[2], dgp[3], cnt4, order4);

    if (big) {
        k_xih<<<dim3(2500, 4), 256, 0, stream>>>(fbf, wihb, lb, xih, 0);
        k_lstm<<<dim3(LSTM_BLOCKS, 4), 256, 0, stream>>>(xih, whhb, order4,
                                                         nbr[0], nbr[1], nbr[2], nbr[3],
                                                         dgp[0], dgp[1], dgp[2], dgp[3], hfin4, 0);
    } else {
        for (int r = 0; r < 4; ++r) {
            k_xih<<<dim3(2500, 1), 256, 0, stream>>>(fbf, wihb, lb, xih, r);
            k_lstm<<<dim3(LSTM_BLOCKS, 1), 256, 0, stream>>>(xih, whhb, order4,
                                                             nbr[0], nbr[1], nbr[2], nbr[3],
                                                             dgp[0], dgp[1], dgp[2], dgp[3], hfin4, r);
        }
    }
    k_projh<<<dim3(625, 2), 256, 0, stream>>>(fbf, hfin4, wstb, wntb, bo,
                                              dgp[0], dgp[1], dgp[2], dgp[3], tmp);
    k_combine<<<5000, 256, 0, stream>>>(tmp, mean, seg, (float*)d_out);
}

// Round 9
// 542.651 us; speedup vs baseline: 4.0904x; 1.1288x over previous
//
#include <hip/hip_runtime.h>

#define NN 40000
#define DDEG 16
#define FF 128
#define OO 128
#define NG 512   // 4*F gates
#define XIH_ELEMS 20480000   // NN*NG u16 per relation
#define L2E 1.4426950408889634f
#define TWO_L2E 2.8853900817779268f

typedef short  s16x8 __attribute__((ext_vector_type(8)));
typedef unsigned short u16x8 __attribute__((ext_vector_type(8)));
typedef unsigned short u16x4 __attribute__((ext_vector_type(4)));
typedef float  f32x4 __attribute__((ext_vector_type(4)));

static_assert(sizeof(s16x8) == 16, "frag size");

__device__ __forceinline__ unsigned short f2bf(float f) {
    unsigned int u = __builtin_bit_cast(unsigned int, f);
    u += 0x7FFFu + ((u >> 16) & 1u);   // RNE
    return (unsigned short)(u >> 16);
}
__device__ __forceinline__ float bf2f(unsigned short s) {
    unsigned int u = ((unsigned int)s) << 16;
    return __builtin_bit_cast(float, u);
}
__device__ __forceinline__ f32x4 splat4(float v) { f32x4 r = {v, v, v, v}; return r; }

// ---- prep: weights -> bf16 with exp2 prescale; Ws/Wn transpose; feat cast ----
// gate-row scale: rows [0,256)+[384,512) (i,f,o): log2e; rows [256,384) (g): 2*log2e
__global__ void k_prep(const float* __restrict__ Wih, const float* __restrict__ Whh,
                       const float* __restrict__ Ws,  const float* __restrict__ Wn,
                       const float* __restrict__ feat,
                       unsigned short* __restrict__ wihb, unsigned short* __restrict__ whhb,
                       unsigned short* __restrict__ wstb, unsigned short* __restrict__ wntb,
                       unsigned short* __restrict__ fbf) {
    int i = blockIdx.x * blockDim.x + threadIdx.x;
    int stride = gridDim.x * blockDim.x;
    for (int idx = i; idx < 4 * NG * FF; idx += stride) {
        int row = (idx >> 7) & 511;
        float s = ((row >> 7) == 2) ? TWO_L2E : L2E;
        wihb[idx] = f2bf(Wih[idx] * s);
        whhb[idx] = f2bf(Whh[idx] * s);
    }
    for (int idx = i; idx < 4 * FF * OO; idx += stride) {
        int r = idx >> 14;
        int rem = idx & 16383;
        int o = rem >> 7;
        int k = rem & 127;
        wstb[idx] = f2bf(Ws[(r << 14) + (k << 7) + o]);
        wntb[idx] = f2bf(Wn[(r << 14) + (k << 7) + o]);
    }
    for (int idx4 = i * 4; idx4 < NN * FF; idx4 += stride * 4) {
        float4 v = *(const float4*)(feat + idx4);
        ushort4 o;
        o.x = f2bf(v.x); o.y = f2bf(v.y); o.z = f2bf(v.z); o.w = f2bf(v.w);
        *(ushort4*)(fbf + idx4) = o;
    }
}

// ---------------- segment mean (seg_ids sorted, G=64), float4 vectorized -----
__global__ void k_segmean(const float* __restrict__ feat, const int* __restrict__ seg,
                          float* __restrict__ mean) {
    int g = blockIdx.x;
    int lo, hi;
    { int a = 0, b = NN; while (a < b) { int m = (a + b) >> 1; if (seg[m] < g) a = m + 1; else b = m; } lo = a; }
    { int a = 0, b = NN; while (a < b) { int m = (a + b) >> 1; if (seg[m] < g + 1) a = m + 1; else b = m; } hi = a; }
    int tid = threadIdx.x;
    int d4 = tid & 31;
    int part = tid >> 5;
    float4 s = {0.f, 0.f, 0.f, 0.f};
    for (int row = lo + part; row < hi; row += 8) {
        float4 v = *(const float4*)(feat + (size_t)row * FF + d4 * 4);
        s.x += v.x; s.y += v.y; s.z += v.z; s.w += v.w;
    }
    __shared__ float ps[8][128];
    ps[part][d4 * 4 + 0] = s.x; ps[part][d4 * 4 + 1] = s.y;
    ps[part][d4 * 4 + 2] = s.z; ps[part][d4 * 4 + 3] = s.w;
    __syncthreads();
    if (tid < 128) {
        float tot = 0.f;
#pragma unroll
        for (int p = 0; p < 8; ++p) tot += ps[p][tid];
        mean[g * FF + tid] = tot / fmaxf((float)(hi - lo), 1.0f);
    }
}

// ---------------- deg bucketing, all 4 relations (two-level histogram) -------
__global__ void k_count(const int* __restrict__ D0, const int* __restrict__ D1,
                        const int* __restrict__ D2, const int* __restrict__ D3,
                        int* __restrict__ cnt4) {
    int r = blockIdx.y;
    const int* dg = (r == 0) ? D0 : (r == 1) ? D1 : (r == 2) ? D2 : D3;
    __shared__ int lcnt[17];
    if (threadIdx.x < 17) lcnt[threadIdx.x] = 0;
    __syncthreads();
    int n = blockIdx.x * blockDim.x + threadIdx.x;
    if (n < NN) { int d = dg[n]; if (d > 0) atomicAdd(&lcnt[d], 1); }
    __syncthreads();
    if (threadIdx.x >= 1 && threadIdx.x < 17 && lcnt[threadIdx.x])
        atomicAdd(&cnt4[r * 64 + threadIdx.x], lcnt[threadIdx.x]);
}
__global__ void k_offsets(int* __restrict__ cnt4) {
    int r = threadIdx.x;
    if (r < 4 && blockIdx.x == 0) {
        int running = 0;
        for (int d = 16; d >= 1; --d) {
            cnt4[r * 64 + 40 + d] = running;
            running += (cnt4[r * 64 + d] + 15) & ~15;
        }
    }
}
__global__ void k_scatter(const int* __restrict__ D0, const int* __restrict__ D1,
                          const int* __restrict__ D2, const int* __restrict__ D3,
                          int* __restrict__ cnt4, int* __restrict__ order4) {
    int r = blockIdx.y;
    const int* dg = (r == 0) ? D0 : (r == 1) ? D1 : (r == 2) ? D2 : D3;
    __shared__ int lcnt[17];
    __shared__ int gbase[17];
    if (threadIdx.x < 17) lcnt[threadIdx.x] = 0;
    __syncthreads();
    int n = blockIdx.x * blockDim.x + threadIdx.x;
    int d = 0, rank = 0;
    if (n < NN) { d = dg[n]; if (d > 0) rank = atomicAdd(&lcnt[d], 1); }
    __syncthreads();
    if (threadIdx.x >= 1 && threadIdx.x < 17 && lcnt[threadIdx.x])
        gbase[threadIdx.x] = atomicAdd(&cnt4[r * 64 + 40 + threadIdx.x], lcnt[threadIdx.x]);
    __syncthreads();
    if (n < NN && d > 0) order4[r * 40960 + gbase[d] + rank] = n;
}

// ---------------- Xih = feat @ Wih[r].T + b(scaled), 8-wave-permuted layout --
// u16 index in 512-row: (T&7)*64 + col*4 + (T>>3) for gate-tile T.
// 32 nodes/block (2 A-sets amortize each B-frag); 4 waves, tiles {w+4j}.
__global__ __launch_bounds__(256, 4) void k_xih(const unsigned short* __restrict__ fbf,
                                                const unsigned short* __restrict__ wihb,
                                                const float* __restrict__ lb,
                                                unsigned short* __restrict__ xih, int rbase) {
    int r = rbase + blockIdx.y;
    unsigned short* xr = xih + (size_t)blockIdx.y * XIH_ELEMS;
    int tid = threadIdx.x;
    int w = tid >> 6;
    int l = tid & 63;
    int n0 = blockIdx.x * 32;
    int col = l & 15, grp = l >> 4;

    f32x4 acc[8][2];
#pragma unroll
    for (int j = 0; j < 8; ++j) {
        float sc = (((w + 4 * j) >> 3) == 2) ? TWO_L2E : L2E;
        f32x4 b = splat4(lb[r * NG + (w + 4 * j) * 16 + col] * sc);
        acc[j][0] = b; acc[j][1] = b;
    }

    s16x8 a0[4], a1[4];
    const unsigned short* ap0 = fbf + (size_t)(n0 + col) * FF + grp * 8;
    const unsigned short* ap1 = fbf + (size_t)(n0 + 16 + col) * FF + grp * 8;
#pragma unroll
    for (int kt = 0; kt < 4; ++kt) {
        a0[kt] = *(const s16x8*)(ap0 + kt * 32);
        a1[kt] = *(const s16x8*)(ap1 + kt * 32);
    }

    const unsigned short* wb = wihb + (size_t)r * NG * FF + col * FF + grp * 8;
#pragma unroll
    for (int j = 0; j < 8; ++j) {
#pragma unroll
        for (int kt = 0; kt < 4; ++kt) {
            s16x8 b = *(const s16x8*)(wb + (size_t)(w + 4 * j) * 16 * FF + kt * 32);
            acc[j][0] = __builtin_amdgcn_mfma_f32_16x16x32_bf16(a0[kt], b, acc[j][0], 0, 0, 0);
            acc[j][1] = __builtin_amdgcn_mfma_f32_16x16x32_bf16(a1[kt], b, acc[j][1], 0, 0, 0);
        }
    }
    // store: tile T=w+4j -> u16 idx (T&7)*64+col*4+(T>>3); j even -> slot w, j odd -> slot w+4
#pragma unroll
    for (int s = 0; s < 2; ++s) {
#pragma unroll
        for (int q = 0; q < 4; ++q) {
            int node = n0 + s * 16 + grp * 4 + q;
            u16x4 ue, uo;
#pragma unroll
            for (int m = 0; m < 4; ++m) {
                ue[m] = f2bf(acc[2 * m][s][q]);
                uo[m] = f2bf(acc[2 * m + 1][s][q]);
            }
            *(u16x4*)(xr + (size_t)node * NG + w * 64 + col * 4) = ue;
            *(u16x4*)(xr + (size_t)node * NG + (w + 4) * 64 + col * 4) = uo;
        }
    }
}

// ---------------- bucketed LSTM: 8 waves x 4 tiles, Whh in regs --------------
// 512 thr; wave w owns tiles {w+8j, j=0..3} -> thread-local i/f/g/o quadruple
// (acc[0..3]) for 4 nodes; 4 activations/thread/step; exp2-domain gates.
#define LSTM_BLOCKS 1280
#define LSTM_GROUPS 2
__global__ __launch_bounds__(512, 4) void k_lstm(const unsigned short* __restrict__ xih,
                                                 const unsigned short* __restrict__ whhb,
                                                 const int* __restrict__ order4,
                                                 const int* __restrict__ N0, const int* __restrict__ N1,
                                                 const int* __restrict__ N2, const int* __restrict__ N3,
                                                 const int* __restrict__ D0, const int* __restrict__ D1,
                                                 const int* __restrict__ D2, const int* __restrict__ D3,
                                                 unsigned short* __restrict__ hfin4, int rbase) {
    int r = rbase + blockIdx.y;
    const unsigned short* xr = xih + (size_t)blockIdx.y * XIH_ELEMS;
    const int* nbr = (r == 0) ? N0 : (r == 1) ? N1 : (r == 2) ? N2 : N3;
    const int* deg = (r == 0) ? D0 : (r == 1) ? D1 : (r == 2) ? D2 : D3;
    const int* order = order4 + r * 40960;
    unsigned short* hfin = hfin4 + (size_t)r * NN * FF;

    __shared__ int nodes[16];
    __shared__ int nbrs[16][16];               // premultiplied byte offsets (node*1024)
    __shared__ unsigned short hbuf[2][2048];   // 2 x (16 rows x 128 dims bf16), XOR-swizzled
    int tid = threadIdx.x;
    int w = tid >> 6, l = tid & 63;
    int col = l & 15, grp = l >> 4;

    // Whh slice: tiles {w+8j}, 16 frags = 64 regs
    const unsigned short* whhp = whhb + (size_t)r * NG * FF + col * FF + grp * 8;
    s16x8 breg[4][4];
#pragma unroll
    for (int j = 0; j < 4; ++j)
#pragma unroll
        for (int kt = 0; kt < 4; ++kt)
            breg[j][kt] = *(const s16x8*)(whhp + (size_t)(w + 8 * j) * 16 * FF + kt * 32);

    const char* xbc = (const char*)(xr + w * 64 + col * 4);

    int rbyte[4];
#pragma unroll
    for (int kt = 0; kt < 4; ++kt)
        rbyte[kt] = (col * 256 + kt * 64 + grp * 16) ^ ((col & 7) << 4);
    int wbyte[4];
#pragma unroll
    for (int q = 0; q < 4; ++q) {
        int node = grp * 4 + q;
        wbyte[q] = (node * 256 + (w * 16 + col) * 2) ^ ((node & 7) << 4);
    }

    for (int gi = 0; gi < LSTM_GROUPS; ++gi) {
        int g0 = (blockIdx.x + gi * LSTM_BLOCKS) * 16;
        __syncthreads();
        if (tid < 16) nodes[tid] = order[g0 + tid];
        __syncthreads();
        if (nodes[0] < 0) continue;          // uniform
        int degv = deg[nodes[0]];

        if (tid < 256) {
            int row = tid >> 4, t = tid & 15;
            int nd = nodes[row]; if (nd < 0) nd = 0;
            nbrs[row][t] = nbr[nd * DDEG + t] << 10;
        }
        __syncthreads();

        float cst[4];
#pragma unroll
        for (int e = 0; e < 4; ++e) cst[e] = 0.f;

        u16x4 cur[4], nxt[4];
#pragma unroll
        for (int q = 0; q < 4; ++q) {
            cur[q] = *(const u16x4*)(xbc + (unsigned)nbrs[grp * 4 + q][0]);
            nxt[q] = cur[q];
        }

        for (int t = 0; t < degv; ++t) {
            if (t + 1 < degv) {
#pragma unroll
                for (int q = 0; q < 4; ++q)
                    nxt[q] = *(const u16x4*)(xbc + (unsigned)nbrs[grp * 4 + q][t + 1]);
            }
            f32x4 acc[4];
#pragma unroll
            for (int j = 0; j < 4; ++j)
#pragma unroll
                for (int q = 0; q < 4; ++q)
                    acc[j][q] = bf2f(cur[q][j]);

            if (t > 0) {
                const char* hrd = (const char*)hbuf[t & 1];
#pragma unroll
                for (int kt = 0; kt < 4; ++kt) {
                    s16x8 ah = *(const s16x8*)(hrd + rbyte[kt]);
#pragma unroll
                    for (int j = 0; j < 4; ++j)
                        acc[j] = __builtin_amdgcn_mfma_f32_16x16x32_bf16(ah, breg[j][kt], acc[j], 0, 0, 0);
                }
            }
            // exp2-domain shared-rcp activations (gates prescaled by log2e / 2log2e):
            // A=2^-i', B=2^-f', C=2^g', D=2^-o'; i*g=(C-1)/((1+A)(C+1)); f*c=c/(1+B);
            // h=o*tanh(cn)=(E-1)/((1+D)(E+1)), E=2^(2*log2e*cn)
            char* hwr = (char*)hbuf[(t + 1) & 1];
#pragma unroll
            for (int q = 0; q < 4; ++q) {
                float A = __builtin_amdgcn_exp2f(-acc[0][q]);
                float B = __builtin_amdgcn_exp2f(-acc[1][q]);
                float C = __builtin_amdgcn_exp2f(acc[2][q]);
                float D = __builtin_amdgcn_exp2f(-acc[3][q]);
                float ig = (C - 1.0f) * __builtin_amdgcn_rcpf((1.0f + A) * (C + 1.0f));
                float fc = cst[q] * __builtin_amdgcn_rcpf(1.0f + B);
                float cv = fc + ig;
                cst[q] = cv;
                float E = __builtin_amdgcn_exp2f(TWO_L2E * cv);
                float hv = (E - 1.0f) * __builtin_amdgcn_rcpf((1.0f + D) * (E + 1.0f));
                *(unsigned short*)(hwr + wbyte[q]) = f2bf(hv);
            }
#pragma unroll
            for (int q = 0; q < 4; ++q) cur[q] = nxt[q];
            __syncthreads();
        }
        // write h_fin from hbuf[degv & 1]: 16 rows x 256B, 8B per thread
        const char* hf = (const char*)hbuf[degv & 1];
        int row = tid >> 5;
        int nd = nodes[row];
        if (nd >= 0) {
            int off = (tid & 31) * 8;
            int byte = (row * 256 + off) ^ ((row & 7) << 4);
            u16x4 v = *(const u16x4*)(hf + byte);
            *(u16x4*)(hfin + (size_t)nd * FF + off / 2) = v;
        }
    }
}

// ---------------- projection: one relation per block -> bf16 partial ---------
__global__ __launch_bounds__(256, 4) void k_projh(const unsigned short* __restrict__ fbf,
                                                  const unsigned short* __restrict__ hfin4,
                                                  const unsigned short* __restrict__ wstb,
                                                  const unsigned short* __restrict__ wntb,
                                                  const float* __restrict__ bo,
                                                  const int* __restrict__ D0, const int* __restrict__ D1,
                                                  const int* __restrict__ D2, const int* __restrict__ D3,
                                                  unsigned short* __restrict__ tmp) {
    int r = blockIdx.y;
    const int* dg = (r == 0) ? D0 : (r == 1) ? D1 : (r == 2) ? D2 : D3;
    int wv = threadIdx.x >> 6, l = threadIdx.x & 63;
    int n0 = blockIdx.x * 64 + wv * 16;
    int col = l & 15, grp = l >> 4;

    s16x8 af[4], ah[4];
    const unsigned short* fp = fbf + (size_t)(n0 + col) * FF + grp * 8;
    const unsigned short* hp = hfin4 + (size_t)r * NN * FF + (size_t)(n0 + col) * FF + grp * 8;
    int dval = dg[n0 + col];
    const s16x8 zfrag = {0, 0, 0, 0, 0, 0, 0, 0};
#pragma unroll
    for (int kt = 0; kt < 4; ++kt) {
        af[kt] = *(const s16x8*)(fp + kt * 32);
        s16x8 h = *(const s16x8*)(hp + kt * 32);
        ah[kt] = (dval > 0) ? h : zfrag;
    }

    f32x4 acc[8];
#pragma unroll
    for (int t = 0; t < 8; ++t) acc[t] = splat4(bo[r * OO + t * 16 + col]);

    const unsigned short* wsb = wstb + (size_t)r * OO * FF + col * FF + grp * 8;
    const unsigned short* wnb = wntb + (size_t)r * OO * FF + col * FF + grp * 8;
#pragma unroll
    for (int kt = 0; kt < 4; ++kt) {
#pragma unroll
        for (int t = 0; t < 8; ++t) {
            s16x8 b1 = *(const s16x8*)(wsb + t * 16 * FF + kt * 32);
            acc[t] = __builtin_amdgcn_mfma_f32_16x16x32_bf16(af[kt], b1, acc[t], 0, 0, 0);
            s16x8 b2 = *(const s16x8*)(wnb + t * 16 * FF + kt * 32);
            acc[t] = __builtin_amdgcn_mfma_f32_16x16x32_bf16(ah[kt], b2, acc[t], 0, 0, 0);
        }
    }
    unsigned short* tp = tmp + (size_t)r * NN * OO;
#pragma unroll
    for (int q = 0; q < 4; ++q) {
        int node = n0 + grp * 4 + q;
#pragma unroll
        for (int t = 0; t < 8; ++t)
            tp[node * OO + t * 16 + col] = f2bf(acc[t][q]);
    }
}

// ---------------- combine: out = mean[seg] + max(p0,p1) + max(p2,p3) ---------
__global__ void k_combine(const unsigned short* __restrict__ tmp,
                          const float* __restrict__ mean, const int* __restrict__ seg,
                          float* __restrict__ out) {
    int i = blockIdx.x * blockDim.x + threadIdx.x;
    int idx4 = i * 4;
    if (idx4 >= NN * OO) return;
    int node = idx4 >> 7;
    int dim = idx4 & 127;
    ushort4 p0 = *(const ushort4*)(tmp + idx4);
    ushort4 p1 = *(const ushort4*)(tmp + (size_t)NN * OO + idx4);
    ushort4 p2 = *(const ushort4*)(tmp + 2 * (size_t)NN * OO + idx4);
    ushort4 p3 = *(const ushort4*)(tmp + 3 * (size_t)NN * OO + idx4);
    float4 mv = *(const float4*)(mean + seg[node] * FF + dim);
    float4 o;
    o.x = mv.x + fmaxf(bf2f(p0.x), bf2f(p1.x)) + fmaxf(bf2f(p2.x), bf2f(p3.x));
    o.y = mv.y + fmaxf(bf2f(p0.y), bf2f(p1.y)) + fmaxf(bf2f(p2.y), bf2f(p3.y));
    o.z = mv.z + fmaxf(bf2f(p0.z), bf2f(p1.z)) + fmaxf(bf2f(p2.z), bf2f(p3.z));
    o.w = mv.w + fmaxf(bf2f(p0.w), bf2f(p1.w)) + fmaxf(bf2f(p2.w), bf2f(p3.w));
    *(float4*)(out + idx4) = o;
}

extern "C" void kernel_launch(void* const* d_in, const int* in_sizes, int n_in,
                              void* d_out, int out_size, void* d_ws, size_t ws_size,
                              hipStream_t stream) {
    const float* feat = (const float*)d_in[0];
    const int* nbr[4] = {(const int*)d_in[1], (const int*)d_in[3], (const int*)d_in[5], (const int*)d_in[7]};
    const int* dgp[4] = {(const int*)d_in[2], (const int*)d_in[4], (const int*)d_in[6], (const int*)d_in[8]};
    const int* seg   = (const int*)d_in[9];
    const float* Wih = (const float*)d_in[10];
    const float* Whh = (const float*)d_in[11];
    const float* lb  = (const float*)d_in[12];
    const float* Ws  = (const float*)d_in[13];
    const float* Wn  = (const float*)d_in[14];
    const float* bo  = (const float*)d_in[15];

    char* ws = (char*)d_ws;
    float*          mean  = (float*)(ws + 0);                      //     32,768
    unsigned short* fbf   = (unsigned short*)(ws + 32768);         // 10,240,000
    unsigned short* wihb  = (unsigned short*)(ws + 10272768);      //    524,288
    unsigned short* whhb  = (unsigned short*)(ws + 10797056);      //    524,288
    unsigned short* wstb  = (unsigned short*)(ws + 11321344);      //    131,072
    unsigned short* wntb  = (unsigned short*)(ws + 11452416);      //    131,072
    unsigned short* xih   = (unsigned short*)(ws + 11583488);      // 4x or 1x 40,960,000

    const int big = (ws_size >= 217039872ULL);
    size_t xih_bytes = big ? 163840000ULL : 40960000ULL;
    unsigned short* hfin4 = (unsigned short*)(ws + 11583488 + xih_bytes);          // 40,960,000
    int*            order4= (int*)(ws + 11583488 + xih_bytes + 40960000);          //    655,360
    int*            cnt4  = (int*)(ws + 11583488 + xih_bytes + 40960000 + 655360); //      1,024
    unsigned short* tmp   = xih;   // xih dead after lstm; 40,960,000 B for 4 bf16 partials

    hipMemsetAsync(order4, 0xFF, 655360, stream);
    hipMemsetAsync(cnt4, 0, 1024, stream);

    k_prep<<<1024, 256, 0, stream>>>(Wih, Whh, Ws, Wn, feat, wihb, whhb, wstb, wntb, fbf);
    k_segmean<<<64, 256, 0, stream>>>(feat, seg, mean);
    k_count<<<dim3(157, 4), 256, 0, stream>>>(dgp[0], dgp[1], dgp[2], dgp[3], cnt4);
    k_offsets<<<1, 64, 0, stream>>>(cnt4);
    k_scatter<<<dim3(157, 4), 256, 0, stream>>>(dgp[0], dgp[1], dgp[2], dgp[3], cnt4, order4);

    if (big) {
        k_xih<<<dim3(1250, 4), 256, 0, stream>>>(fbf, wihb, lb, xih, 0);
        k_lstm<<<dim3(LSTM_BLOCKS, 4), 512, 0, stream>>>(xih, whhb, order4,
                                                         nbr[0], nbr[1], nbr[2], nbr[3],
                                                         dgp[0], dgp[1], dgp[2], dgp[3], hfin4, 0);
    } else {
        for (int r = 0; r < 4; ++r) {
            k_xih<<<dim3(1250, 1), 256, 0, stream>>>(fbf, wihb, lb, xih, r);
            k_lstm<<<dim3(LSTM_BLOCKS, 1), 512, 0, stream>>>(xih, whhb, order4,
                                                             nbr[0], nbr[1], nbr[2], nbr[3],
                                                             dgp[0], dgp[1], dgp[2], dgp[3], hfin4, r);
        }
    }
    k_projh<<<dim3(625, 4), 256, 0, stream>>>(fbf, hfin4, wstb, wntb, bo,
                                              dgp[0], dgp[1], dgp[2], dgp[3], tmp);
    k_combine<<<5000, 256, 0, stream>>>(tmp, mean, seg, (float*)d_out);
}